// Round 9
// baseline (2774.212 us; speedup 1.0000x reference)
//
#include <hip/hip_runtime.h>
#include <math.h>

#define N_NODES 100000
#define N_EDGES 1600000
#define RREL 4
#define DDIM 128
#define KDIM 512      // RREL*DDIM
#define NKEY 400000   // N_NODES*RREL
#define SRCMASK 0x03FFFFFFu   // low 26 bits: src id; bits 26..31: dst&63 (local node id)

typedef __bf16 bf16x8 __attribute__((ext_vector_type(8)));
typedef float f32x4 __attribute__((ext_vector_type(4)));

__device__ __forceinline__ float bflo(unsigned u){ return __builtin_bit_cast(float, u << 16); }
__device__ __forceinline__ float bfhi(unsigned u){ return __builtin_bit_cast(float, u & 0xffff0000u); }
__device__ __forceinline__ unsigned f2bf(float f){
  unsigned u = __builtin_bit_cast(unsigned, f);
  return (u + 0x7fffu + ((u >> 16) & 1u)) >> 16;   // RNE, finite inputs
}
__device__ __forceinline__ int iclamp(int v, int lo, int hi){
  return v < lo ? lo : (v > hi ? hi : v);
}

// ---------------- counting sort of edges by key = et*N + dst ----------------
// (rel-major so each (block of 64 dst nodes, rel) owns a CONTIGUOUS edge range)

__global__ void hist_kernel(const int* __restrict__ dst, const int* __restrict__ et,
                            int* __restrict__ counts){
  int e = blockIdx.x * 256 + threadIdx.x;
  int d = iclamp(dst[e], 0, N_NODES - 1);
  int t = iclamp(et[e], 0, RREL - 1);
  atomicAdd(&counts[t * N_NODES + d], 1);
}

__global__ void scan_local(const int* __restrict__ in, int* __restrict__ out,
                           int* __restrict__ bsums, int K){
  __shared__ int s[1024];
  int t = threadIdx.x;
  int i = blockIdx.x * 1024 + t;
  int v = (i < K) ? in[i] : 0;
  s[t] = v; __syncthreads();
  for (int off = 1; off < 1024; off <<= 1){
    int x = (t >= off) ? s[t - off] : 0;
    __syncthreads();
    s[t] += x;
    __syncthreads();
  }
  if (i < K) out[i] = s[t] - v;           // exclusive within block
  if (t == 1023) bsums[blockIdx.x] = s[t];
}

__global__ void scan_sums(int* __restrict__ b, int nb){
  __shared__ int s[1024];
  int t = threadIdx.x;
  int v = (t < nb) ? b[t] : 0;
  s[t] = v; __syncthreads();
  for (int off = 1; off < 1024; off <<= 1){
    int x = (t >= off) ? s[t - off] : 0;
    __syncthreads();
    s[t] += x;
    __syncthreads();
  }
  if (t < nb) b[t] = s[t] - v;            // exclusive block prefix
}

__global__ void scan_add(int* __restrict__ out, int* __restrict__ cursor,
                         const int* __restrict__ bsums, int K, int total){
  int t = threadIdx.x;
  int i = blockIdx.x * 1024 + t;
  if (i < K){
    int v = out[i] + bsums[blockIdx.x];
    out[i] = v;
    cursor[i] = v;
  }
  if (i == 0) out[K] = total;
}

__global__ void scatter_kernel(const int* __restrict__ src, const int* __restrict__ dst,
                               const int* __restrict__ et, int* __restrict__ cursor,
                               unsigned* __restrict__ ssrc){
  int e = blockIdx.x * 256 + threadIdx.x;
  int d = iclamp(dst[e], 0, N_NODES - 1);
  int t = iclamp(et[e], 0, RREL - 1);
  int key = t * N_NODES + d;
  int p = atomicAdd(&cursor[key], 1);
  p = iclamp(p, 0, N_EDGES - 1);
  // pack src (26 bits used; <2^17 actual) with local node id d&63 (block n0 is 64-aligned)
  ssrc[p] = (unsigned)iclamp(src[e], 0, N_NODES - 1) | ((unsigned)(d & 63) << 26);
}

// ---------------- x (f32 [N,128]) -> packed bf16 pairs [N,64] uints ----------------

__global__ void convert_x(const float* __restrict__ x, unsigned* __restrict__ xb){
  int i = blockIdx.x * 256 + threadIdx.x;      // over N*64
  float2 v = *(const float2*)(x + (size_t)i * 2);
  xb[i] = f2bf(v.x) | (f2bf(v.y) << 16);
}

// ---------------- W (f32 [512][128]) -> Bt bf16 [128][512] ----------------

__global__ void transpose_w(const float* __restrict__ W, unsigned short* __restrict__ Bt){
  int idx = blockIdx.x * 256 + threadIdx.x;    // 65536
  int k = idx >> 7, n = idx & 127;
  Bt[n * KDIM + k] = (unsigned short)f2bf(W[idx]);
}

// ---------------- fused layer: block-cooperative mean -> @W -> tanh ----------------
// Block = 64 dst nodes. Per relation, the block's edges are CONTIGUOUS (key = r*N+dst).
// Aggregation: whole wave cooperates on ONE edge — hin[cur*64+lane] is a coalesced 256B
// load (1 instr, 4 lines); each lane atomicAdds its 2 dims into agg[64][132] (ds_add_f32).
// Edges wave-strided -> no per-lane serial gather chain, no max-degree divergence tail;
// unroll-4 keeps 4 independent row loads in flight with ~3 VGPR each (nothing to spill —
// rounds 2-8 showed the register-pipeline approach always coalesces or spills).
// Then barrier; each lane reads its proven MFMA A-slice from LDS (pad 132 -> 2-way banks),
// scales by 1/cnt, packs bf16, MFMA (unchanged layout/epilogue).

__global__ __launch_bounds__(256) void fused_layer(const unsigned* __restrict__ hin,
                                                   const unsigned* __restrict__ ssrc,
                                                   const int* __restrict__ offs,
                                                   const __bf16* __restrict__ Bt,
                                                   unsigned short* __restrict__ hout){
  __shared__ float agg[64][132];   // 33792 B; pad 132 so l15-strided reads are 2-way

  int tid = threadIdx.x;
  int w = tid >> 6, lane = tid & 63;
  int l15 = lane & 15, quad = lane >> 4;
  int n0 = blockIdx.x * 64;
  int nn = (N_NODES - n0 < 64) ? (N_NODES - n0) : 64;   // valid nodes this block
  int n0w = n0 + w * 16;

  f32x4 accC[8];
  #pragma unroll
  for (int tc = 0; tc < 8; tc++) accC[tc] = (f32x4){0.f, 0.f, 0.f, 0.f};

  float* af_ = &agg[0][0];

  for (int r = 0; r < RREL; r++){
    __syncthreads();                       // prev rel's LDS reads done
    for (int idx = tid; idx < 64 * 132; idx += 256) af_[idx] = 0.f;
    __syncthreads();

    // ---- accumulate: wave-strided over the block's contiguous edge range
    int kbase = r * N_NODES + n0;
    int ebeg = offs[kbase];
    int eend = offs[kbase + nn];
    int e = ebeg + w;
    for (; e + 12 < eend; e += 16){
      int eu = __builtin_amdgcn_readfirstlane(e);
      unsigned w0 = ssrc[eu], w1 = ssrc[eu + 4], w2 = ssrc[eu + 8], w3 = ssrc[eu + 12];
      unsigned q0 = hin[(size_t)(w0 & SRCMASK) * 64 + lane];
      unsigned q1 = hin[(size_t)(w1 & SRCMASK) * 64 + lane];
      unsigned q2 = hin[(size_t)(w2 & SRCMASK) * 64 + lane];
      unsigned q3 = hin[(size_t)(w3 & SRCMASK) * 64 + lane];
      atomicAdd(&agg[w0 >> 26][2 * lane],     bflo(q0));
      atomicAdd(&agg[w0 >> 26][2 * lane + 1], bfhi(q0));
      atomicAdd(&agg[w1 >> 26][2 * lane],     bflo(q1));
      atomicAdd(&agg[w1 >> 26][2 * lane + 1], bfhi(q1));
      atomicAdd(&agg[w2 >> 26][2 * lane],     bflo(q2));
      atomicAdd(&agg[w2 >> 26][2 * lane + 1], bfhi(q2));
      atomicAdd(&agg[w3 >> 26][2 * lane],     bflo(q3));
      atomicAdd(&agg[w3 >> 26][2 * lane + 1], bfhi(q3));
    }
    for (; e < eend; e += 4){
      int eu = __builtin_amdgcn_readfirstlane(e);
      unsigned w0 = ssrc[eu];
      unsigned q0 = hin[(size_t)(w0 & SRCMASK) * 64 + lane];
      atomicAdd(&agg[w0 >> 26][2 * lane],     bflo(q0));
      atomicAdd(&agg[w0 >> 26][2 * lane + 1], bfhi(q0));
    }
    __syncthreads();

    // ---- pack A-frags from LDS + MFMA (proven fragment layout)
    int lnm = w * 16 + l15;                // this lane's node (row of agg)
    int n2 = n0 + lnm;
    int ob = r * N_NODES + iclamp(n2, 0, N_NODES - 1);
    int cb = offs[ob], ce = offs[ob + 1];
    int cnt = ce - cb;
    float sc = (cnt > 0 && n2 < N_NODES) ? 1.0f / (float)cnt : 0.0f;

    #pragma unroll
    for (int s = 0; s < 4; s++){
      const float4* ap = (const float4*)&agg[lnm][s * 32 + quad * 8];
      float4 x0 = ap[0], x1 = ap[1];
      uint4 pv;
      pv.x = f2bf(x0.x * sc) | (f2bf(x0.y * sc) << 16);
      pv.y = f2bf(x0.z * sc) | (f2bf(x0.w * sc) << 16);
      pv.z = f2bf(x1.x * sc) | (f2bf(x1.y * sc) << 16);
      pv.w = f2bf(x1.z * sc) | (f2bf(x1.w * sc) << 16);
      bf16x8 af = __builtin_bit_cast(bf16x8, pv);
      const __bf16* bbase = Bt + r * 128 + s * 32 + quad * 8;
      #pragma unroll
      for (int tc = 0; tc < 8; tc++){
        bf16x8 bfr = *(const bf16x8*)(bbase + (size_t)(tc * 16 + l15) * KDIM);
        accC[tc] = __builtin_amdgcn_mfma_f32_16x16x32_bf16(af, bfr, accC[tc], 0, 0, 0);
      }
    }
  }

  // epilogue: tanh, store bf16. C layout: col=l15, row=quad*4+reg
  #pragma unroll
  for (int tc = 0; tc < 8; tc++){
    #pragma unroll
    for (int reg = 0; reg < 4; reg++){
      int n2 = n0w + quad * 4 + reg;
      if (n2 < N_NODES){
        float v = tanhf(accC[tc][reg]);
        hout[(size_t)n2 * 128 + tc * 16 + l15] = (unsigned short)f2bf(v);
      }
    }
  }
}

// ---------------- z precompute: z[n][r][2] = h2[n] . W3_r  (head linearity) ----------------

__global__ void compute_z(const unsigned* __restrict__ h2, const float* __restrict__ W3f,
                          float* __restrict__ zt){
  int n = blockIdx.x * 4 + (threadIdx.x >> 6);
  int lane = threadIdx.x & 63;
  unsigned u = h2[(size_t)n * 64 + lane];
  float a = bflo(u), b = bfhi(u);
  float p[8];
  #pragma unroll
  for (int r = 0; r < RREL; r++){
    float4 wv = *(const float4*)(W3f + r * 256 + lane * 4);
    p[r * 2]     = a * wv.x + b * wv.z;
    p[r * 2 + 1] = a * wv.y + b * wv.w;
  }
  #pragma unroll
  for (int m = 32; m >= 1; m >>= 1){
    #pragma unroll
    for (int j = 0; j < 8; j++) p[j] += __shfl_xor(p[j], m);
  }
  if (lane == 0){
    *(float4*)(zt + (size_t)n * 8)     = (float4){p[0], p[1], p[2], p[3]};
    *(float4*)(zt + (size_t)n * 8 + 4) = (float4){p[4], p[5], p[6], p[7]};
  }
}

// ---------------- head: thread per (node,rel); key = r*N+n; mean z -> reduce -> softmax ----

__global__ void fused_head2(const float* __restrict__ zt,
                            const unsigned* __restrict__ ssrc,
                            const int* __restrict__ offs,
                            float* __restrict__ out){
  int t = blockIdx.x * 256 + threadIdx.x;
  if (t >= NKEY) return;                  // whole waves exit; 4-groups stay intact
  int n = t >> 2, r = t & 3;
  int k2 = r * N_NODES + n;
  int beg = iclamp(offs[k2], 0, N_EDGES);
  int end = iclamp(offs[k2 + 1], beg, N_EDGES);
  float a0 = 0.f, a1 = 0.f, b0 = 0.f, b1 = 0.f, c0 = 0.f, c1 = 0.f, d0 = 0.f, d1 = 0.f;
  int i = beg;
  for (; i + 4 <= end; i += 4){
    int s0 = (int)(ssrc[i]     & SRCMASK);
    int s1 = (int)(ssrc[i + 1] & SRCMASK);
    int s2 = (int)(ssrc[i + 2] & SRCMASK);
    int s3 = (int)(ssrc[i + 3] & SRCMASK);
    float2 v0 = *(const float2*)(zt + (size_t)s0 * 8 + r * 2);
    float2 v1 = *(const float2*)(zt + (size_t)s1 * 8 + r * 2);
    float2 v2 = *(const float2*)(zt + (size_t)s2 * 8 + r * 2);
    float2 v3 = *(const float2*)(zt + (size_t)s3 * 8 + r * 2);
    a0 += v0.x; a1 += v0.y;
    b0 += v1.x; b1 += v1.y;
    c0 += v2.x; c1 += v2.y;
    d0 += v3.x; d1 += v3.y;
  }
  for (; i < end; i++){
    int s = (int)(ssrc[i] & SRCMASK);
    float2 v = *(const float2*)(zt + (size_t)s * 8 + r * 2);
    a0 += v.x; a1 += v.y;
  }
  int cnt = end - beg;
  float sc = (cnt > 0) ? 1.0f / (float)cnt : 0.0f;
  float dA = (a0 + b0 + c0 + d0) * sc;
  float dB = (a1 + b1 + c1 + d1) * sc;
  // sum the 4 relations (4 consecutive lanes of this wave)
  dA += __shfl_xor(dA, 1); dB += __shfl_xor(dB, 1);
  dA += __shfl_xor(dA, 2); dB += __shfl_xor(dB, 2);
  if (r == 0){
    float mx = fmaxf(dA, dB);
    float e0 = __expf(dA - mx), e1 = __expf(dB - mx);
    float inv = 1.0f / (e0 + e1);
    *(float2*)(out + 2 * n) = (float2){e0 * inv, e1 * inv};            // softmax [N,2]
    *(float2*)(out + 2 * N_NODES + 2 * n) = (float2){dA, dB};          // logits  [N,2]
  }
}

// ---------------- launch ----------------

extern "C" void kernel_launch(void* const* d_in, const int* in_sizes, int n_in,
                              void* d_out, int out_size, void* d_ws, size_t ws_size,
                              hipStream_t stream){
  const float* x  = (const float*)d_in[0];
  const int* ei   = (const int*)d_in[1];
  const int* et   = (const int*)d_in[2];
  const float* W1 = (const float*)d_in[3];
  const float* W2 = (const float*)d_in[4];
  const float* W3 = (const float*)d_in[5];
  float* out = (float*)d_out;
  const int* src = ei;
  const int* dst = ei + N_EDGES;

  // workspace layout: ~61 MB total
  char* p = (char*)d_ws;
  auto alloc = [&](size_t bytes) -> char* {
    char* q = p; p += (bytes + 63) & ~(size_t)63; return q;
  };
  int* counts = (int*)alloc((size_t)NKEY * 4);          // reused as cursor
  int* cursor = counts;
  int* offs   = (int*)alloc((size_t)(NKEY + 1) * 4);
  int* bsums  = (int*)alloc(1024 * 4);
  unsigned* ssrc = (unsigned*)alloc((size_t)N_EDGES * 4);   // packed src | (dst&63)<<26
  unsigned short* Bt = (unsigned short*)alloc((size_t)DDIM * KDIM * 2);
  unsigned short* h1 = (unsigned short*)alloc((size_t)N_NODES * DDIM * 2);
  unsigned short* h2 = (unsigned short*)alloc((size_t)N_NODES * DDIM * 2);
  unsigned* xb = (unsigned*)h2;   // x-as-bf16 lives in h2's slot (dead until layer-2 output)
  float* zt = (float*)h1;         // z table aliases h1 (dead after layer-2 reads it)

  // sort edges by (relation, dst)
  hipMemsetAsync(counts, 0, (size_t)NKEY * 4, stream);
  hist_kernel<<<N_EDGES / 256, 256, 0, stream>>>(dst, et, counts);
  int nb = (NKEY + 1023) / 1024;  // 391
  scan_local<<<nb, 1024, 0, stream>>>(counts, offs, bsums, NKEY);
  scan_sums<<<1, 1024, 0, stream>>>(bsums, nb);
  scan_add<<<nb, 1024, 0, stream>>>(offs, cursor, bsums, NKEY, N_EDGES);
  scatter_kernel<<<N_EDGES / 256, 256, 0, stream>>>(src, dst, et, cursor, ssrc);

  int fgrid = (N_NODES + 63) / 64;  // 1563

  // layer 1: x -> packed bf16, agg -> @W1 -> tanh -> h1
  convert_x<<<(N_NODES * 64) / 256, 256, 0, stream>>>(x, xb);
  transpose_w<<<(DDIM * KDIM) / 256, 256, 0, stream>>>(W1, Bt);
  fused_layer<<<fgrid, 256, 0, stream>>>(xb, ssrc, offs, (const __bf16*)Bt, h1);
  // layer 2: h1 -> h2 (xb dead from here on)
  transpose_w<<<(DDIM * KDIM) / 256, 256, 0, stream>>>(W2, Bt);
  fused_layer<<<fgrid, 256, 0, stream>>>((const unsigned*)h1, ssrc, offs, (const __bf16*)Bt, h2);
  // layer 3 head: z = h2 @ W3 per relation (8 f32/node), then 8 B/edge gather + softmax
  compute_z<<<N_NODES / 4, 256, 0, stream>>>((const unsigned*)h2, W3, zt);
  fused_head2<<<(NKEY + 255) / 256, 256, 0, stream>>>(zt, ssrc, offs, out);
}

// Round 10
// 798.323 us; speedup vs baseline: 3.4751x; 3.4751x over previous
//
#include <hip/hip_runtime.h>
#include <math.h>

#define N_NODES 100000
#define N_EDGES 1600000
#define RREL 4
#define DDIM 128
#define KDIM 512      // RREL*DDIM
#define NKEY 400000   // N_NODES*RREL

typedef __bf16 bf16x8 __attribute__((ext_vector_type(8)));
typedef float f32x4 __attribute__((ext_vector_type(4)));

__device__ __forceinline__ float bflo(unsigned u){ return __builtin_bit_cast(float, u << 16); }
__device__ __forceinline__ float bfhi(unsigned u){ return __builtin_bit_cast(float, u & 0xffff0000u); }
__device__ __forceinline__ unsigned f2bf(float f){
  unsigned u = __builtin_bit_cast(unsigned, f);
  return (u + 0x7fffu + ((u >> 16) & 1u)) >> 16;   // RNE, finite inputs
}
__device__ __forceinline__ int iclamp(int v, int lo, int hi){
  return v < lo ? lo : (v > hi ? hi : v);
}

#define GLL(gp, lp) __builtin_amdgcn_global_load_lds( \
    (const __attribute__((address_space(1))) void*)(gp), \
    (__attribute__((address_space(3))) void*)(lp), 16, 0, 0)

// ---------------- counting sort of edges by key = dst*4 + et ----------------

__global__ void hist_kernel(const int* __restrict__ dst, const int* __restrict__ et,
                            int* __restrict__ counts){
  int e = blockIdx.x * 256 + threadIdx.x;
  int key = iclamp(dst[e] * RREL + et[e], 0, NKEY - 1);
  atomicAdd(&counts[key], 1);
}

__global__ void scan_local(const int* __restrict__ in, int* __restrict__ out,
                           int* __restrict__ bsums, int K){
  __shared__ int s[1024];
  int t = threadIdx.x;
  int i = blockIdx.x * 1024 + t;
  int v = (i < K) ? in[i] : 0;
  s[t] = v; __syncthreads();
  for (int off = 1; off < 1024; off <<= 1){
    int x = (t >= off) ? s[t - off] : 0;
    __syncthreads();
    s[t] += x;
    __syncthreads();
  }
  if (i < K) out[i] = s[t] - v;           // exclusive within block
  if (t == 1023) bsums[blockIdx.x] = s[t];
}

__global__ void scan_sums(int* __restrict__ b, int nb){
  __shared__ int s[1024];
  int t = threadIdx.x;
  int v = (t < nb) ? b[t] : 0;
  s[t] = v; __syncthreads();
  for (int off = 1; off < 1024; off <<= 1){
    int x = (t >= off) ? s[t - off] : 0;
    __syncthreads();
    s[t] += x;
    __syncthreads();
  }
  if (t < nb) b[t] = s[t] - v;            // exclusive block prefix
}

__global__ void scan_add(int* __restrict__ out, int* __restrict__ cursor,
                         const int* __restrict__ bsums, int K, int total){
  int t = threadIdx.x;
  int i = blockIdx.x * 1024 + t;
  if (i < K){
    int v = out[i] + bsums[blockIdx.x];
    out[i] = v;
    cursor[i] = v;
  }
  if (i == 0) out[K] = total;
}

__global__ void scatter_kernel(const int* __restrict__ src, const int* __restrict__ dst,
                               const int* __restrict__ et, int* __restrict__ cursor,
                               int* __restrict__ ssrc){
  int e = blockIdx.x * 256 + threadIdx.x;
  int key = iclamp(dst[e] * RREL + et[e], 0, NKEY - 1);
  int p = atomicAdd(&cursor[key], 1);
  p = iclamp(p, 0, N_EDGES - 1);
  ssrc[p] = iclamp(src[e], 0, N_NODES - 1);
}

// ---------------- x (f32 [N,128]) -> packed bf16 pairs [N,64] uints ----------------

__global__ void convert_x(const float* __restrict__ x, unsigned* __restrict__ xb){
  int i = blockIdx.x * 256 + threadIdx.x;      // over N*64
  float2 v = *(const float2*)(x + (size_t)i * 2);
  xb[i] = f2bf(v.x) | (f2bf(v.y) << 16);
}

// ---------------- W (f32 [512][128]) -> Bt bf16 [128][512] ----------------

__global__ void transpose_w(const float* __restrict__ W, unsigned short* __restrict__ Bt){
  int idx = blockIdx.x * 256 + threadIdx.x;    // 65536
  int k = idx >> 7, n = idx & 127;
  Bt[n * KDIM + k] = (unsigned short)f2bf(W[idx]);
}

// ---------------- fused layer: LDS-staged gather -> mean -> @W -> tanh ----------------
// Wave = 16 nodes (l15), quad = lane>>4. Per relation, step i stages edge i of ALL 16
// nodes via 4 global_load_lds instructions (each: 64 lanes x 16B = 4 rows of 256 B) into
// the wave's PRIVATE LDS region (no barriers). 64 cache lines in flight per step vs 4 in
// the register scheme (r2-r8: register pipelines always coalesced or spilled). Double
// buffer + counted vmcnt(4): stage i+1 flies under accumulate i. Lanes past a node's
// degree read a zero-row (adds 0.0 -> unconditional accumulate). Source-chunk XOR swizzle
// (chunk = p ^ row) makes the strided ds_read_b128 2-way (free); LDS dest stays linear
// (global_load_lds requirement). Index loads are VECTOR loads (vmcnt) — r9 lesson: scalar
// loads share lgkmcnt with ds ops and serialize everything.

__global__ __launch_bounds__(256) void fused_layer(const unsigned* __restrict__ hin,
                                                   const int* __restrict__ ssrc,
                                                   const int* __restrict__ offs,
                                                   const __bf16* __restrict__ Bt,
                                                   const char* __restrict__ zrow,
                                                   unsigned short* __restrict__ hout){
  __shared__ uint4 smem4[2048];          // 4 waves x 2 bufs x 16 rows x 256 B = 32 KB

  int tid = threadIdx.x;
  int w = tid >> 6, lane = tid & 63;
  int l15 = lane & 15, quad = lane >> 4;
  int n0w = blockIdx.x * 64 + w * 16;
  int n = n0w + l15;                     // this lane's node
  int valid = (n < N_NODES);
  const char* hinB = (const char*)hin;
  uint4* lw = &smem4[w << 9];            // this wave's 512-uint4 region

  f32x4 accC[8];
  #pragma unroll
  for (int tc = 0; tc < 8; tc++) accC[tc] = (f32x4){0.f, 0.f, 0.f, 0.f};

  // per-lane staging constants: instr j serves row g = j*4+quad at position p = l15;
  // source chunk q = p ^ g (inverse of the read-side swizzle)
  int q0 = (l15 ^ (quad)) * 16;
  int q1 = (l15 ^ (4 + quad)) * 16;
  int q2 = (l15 ^ (8 + quad)) * 16;
  int q3 = (l15 ^ (12 + quad)) * 16;

  #pragma unroll
  for (int r = 0; r < RREL; r++){
    int ob = valid ? (n * 4 + r) : 0;
    int beg = iclamp(offs[ob], 0, N_EDGES);
    int end = iclamp(offs[ob + 1], beg, N_EDGES);
    if (!valid){ beg = 0; end = 0; }
    int deg = end - beg;

    int trip = deg;                      // wave-uniform step count = max degree
    #pragma unroll
    for (int k = 1; k < 64; k <<= 1){
      int o = __shfl_xor(trip, k);
      trip = trip > o ? trip : o;
    }

    float ac[32];
    #pragma unroll
    for (int j = 0; j < 32; j++) ac[j] = 0.f;

    if (trip > 0){
      // per-instruction node ranges: row g = j*4+quad -> lane g holds that node's beg/end
      int bg0 = __shfl(beg, quad),      eg0 = __shfl(end, quad);
      int bg1 = __shfl(beg, 4 + quad),  eg1 = __shfl(end, 4 + quad);
      int bg2 = __shfl(beg, 8 + quad),  eg2 = __shfl(end, 8 + quad);
      int bg3 = __shfl(beg, 12 + quad), eg3 = __shfl(end, 12 + quad);

      // prologue: indices + stage for step 0 into buf 0
      int sv0 = ssrc[iclamp(bg0, 0, N_EDGES - 1)];
      int sv1 = ssrc[iclamp(bg1, 0, N_EDGES - 1)];
      int sv2 = ssrc[iclamp(bg2, 0, N_EDGES - 1)];
      int sv3 = ssrc[iclamp(bg3, 0, N_EDGES - 1)];
      {
        const char* a0 = (0 < eg0 - bg0) ? hinB + (size_t)(unsigned)sv0 * 256 + q0 : zrow + q0;
        const char* a1 = (0 < eg1 - bg1) ? hinB + (size_t)(unsigned)sv1 * 256 + q1 : zrow + q1;
        const char* a2 = (0 < eg2 - bg2) ? hinB + (size_t)(unsigned)sv2 * 256 + q2 : zrow + q2;
        const char* a3 = (0 < eg3 - bg3) ? hinB + (size_t)(unsigned)sv3 * 256 + q3 : zrow + q3;
        GLL(a0, lw + 0);
        GLL(a1, lw + 64);
        GLL(a2, lw + 128);
        GLL(a3, lw + 192);
      }

      for (int i = 0; i < trip; i++){
        int b = i & 1;
        if (i + 1 < trip){
          // indices for step i+1 (vector loads; compiler waits on values before GLL)
          sv0 = ssrc[iclamp(bg0 + i + 1, 0, N_EDGES - 1)];
          sv1 = ssrc[iclamp(bg1 + i + 1, 0, N_EDGES - 1)];
          sv2 = ssrc[iclamp(bg2 + i + 1, 0, N_EDGES - 1)];
          sv3 = ssrc[iclamp(bg3 + i + 1, 0, N_EDGES - 1)];
          uint4* db = lw + ((b ^ 1) << 8);
          const char* a0 = (i + 1 < eg0 - bg0) ? hinB + (size_t)(unsigned)sv0 * 256 + q0 : zrow + q0;
          const char* a1 = (i + 1 < eg1 - bg1) ? hinB + (size_t)(unsigned)sv1 * 256 + q1 : zrow + q1;
          const char* a2 = (i + 1 < eg2 - bg2) ? hinB + (size_t)(unsigned)sv2 * 256 + q2 : zrow + q2;
          const char* a3 = (i + 1 < eg3 - bg3) ? hinB + (size_t)(unsigned)sv3 * 256 + q3 : zrow + q3;
          GLL(a0, db + 0);
          GLL(a1, db + 64);
          GLL(a2, db + 128);
          GLL(a3, db + 192);
          // allow stage i+1 (4 newest) to stay in flight; stage i must be complete
          asm volatile("s_waitcnt vmcnt(4)" ::: "memory");
        } else {
          asm volatile("s_waitcnt vmcnt(0)" ::: "memory");
        }
        __builtin_amdgcn_sched_barrier(0);

        // accumulate step i from buf b: row l15, chunk (w*4+quad)^l15 (swizzled read)
        const uint4* rb = lw + (b << 8) + (l15 << 4);
        uint4 u0 = rb[(0 * 4 + quad) ^ l15];
        uint4 u1 = rb[(1 * 4 + quad) ^ l15];
        uint4 u2 = rb[(2 * 4 + quad) ^ l15];
        uint4 u3 = rb[(3 * 4 + quad) ^ l15];
        ac[ 0] += bflo(u0.x); ac[ 1] += bfhi(u0.x); ac[ 2] += bflo(u0.y); ac[ 3] += bfhi(u0.y);
        ac[ 4] += bflo(u0.z); ac[ 5] += bfhi(u0.z); ac[ 6] += bflo(u0.w); ac[ 7] += bfhi(u0.w);
        ac[ 8] += bflo(u1.x); ac[ 9] += bfhi(u1.x); ac[10] += bflo(u1.y); ac[11] += bfhi(u1.y);
        ac[12] += bflo(u1.z); ac[13] += bfhi(u1.z); ac[14] += bflo(u1.w); ac[15] += bfhi(u1.w);
        ac[16] += bflo(u2.x); ac[17] += bfhi(u2.x); ac[18] += bflo(u2.y); ac[19] += bfhi(u2.y);
        ac[20] += bflo(u2.z); ac[21] += bfhi(u2.z); ac[22] += bflo(u2.w); ac[23] += bfhi(u2.w);
        ac[24] += bflo(u3.x); ac[25] += bfhi(u3.x); ac[26] += bflo(u3.y); ac[27] += bfhi(u3.y);
        ac[28] += bflo(u3.z); ac[29] += bfhi(u3.z); ac[30] += bflo(u3.w); ac[31] += bfhi(u3.w);
      }
    }

    float sc = (deg > 0) ? 1.0f / (float)deg : 0.0f;

    // 4 MFMA K-steps for this relation; A-frag packed from ac (unchanged, verified)
    #pragma unroll
    for (int s = 0; s < 4; s++){
      uint4 pv;
      pv.x = f2bf(ac[s * 8 + 0] * sc) | (f2bf(ac[s * 8 + 1] * sc) << 16);
      pv.y = f2bf(ac[s * 8 + 2] * sc) | (f2bf(ac[s * 8 + 3] * sc) << 16);
      pv.z = f2bf(ac[s * 8 + 4] * sc) | (f2bf(ac[s * 8 + 5] * sc) << 16);
      pv.w = f2bf(ac[s * 8 + 6] * sc) | (f2bf(ac[s * 8 + 7] * sc) << 16);
      bf16x8 af = __builtin_bit_cast(bf16x8, pv);
      const __bf16* bbase = Bt + r * 128 + s * 32 + quad * 8;
      #pragma unroll
      for (int tc = 0; tc < 8; tc++){
        bf16x8 bfr = *(const bf16x8*)(bbase + (size_t)(tc * 16 + l15) * KDIM);
        accC[tc] = __builtin_amdgcn_mfma_f32_16x16x32_bf16(af, bfr, accC[tc], 0, 0, 0);
      }
    }
  }

  // epilogue: tanh, store bf16. C layout: col=l15, row=quad*4+reg
  #pragma unroll
  for (int tc = 0; tc < 8; tc++){
    #pragma unroll
    for (int reg = 0; reg < 4; reg++){
      int n2 = n0w + quad * 4 + reg;
      if (n2 < N_NODES){
        float v = tanhf(accC[tc][reg]);
        hout[(size_t)n2 * 128 + tc * 16 + l15] = (unsigned short)f2bf(v);
      }
    }
  }
}

// ---------------- z precompute: z[n][r][2] = h2[n] . W3_r  (head linearity) ----------------

__global__ void compute_z(const unsigned* __restrict__ h2, const float* __restrict__ W3f,
                          float* __restrict__ zt){
  int n = blockIdx.x * 4 + (threadIdx.x >> 6);
  int lane = threadIdx.x & 63;
  unsigned u = h2[(size_t)n * 64 + lane];
  float a = bflo(u), b = bfhi(u);
  float p[8];
  #pragma unroll
  for (int r = 0; r < RREL; r++){
    float4 wv = *(const float4*)(W3f + r * 256 + lane * 4);
    p[r * 2]     = a * wv.x + b * wv.z;
    p[r * 2 + 1] = a * wv.y + b * wv.w;
  }
  #pragma unroll
  for (int m = 32; m >= 1; m >>= 1){
    #pragma unroll
    for (int j = 0; j < 8; j++) p[j] += __shfl_xor(p[j], m);
  }
  if (lane == 0){
    *(float4*)(zt + (size_t)n * 8)     = (float4){p[0], p[1], p[2], p[3]};
    *(float4*)(zt + (size_t)n * 8 + 4) = (float4){p[4], p[5], p[6], p[7]};
  }
}

// ---------------- head: thread per (node,rel) key; mean of z[src,rel] -> reduce -> softmax ----

__global__ void fused_head2(const float* __restrict__ zt,
                            const int* __restrict__ ssrc,
                            const int* __restrict__ offs,
                            float* __restrict__ out){
  int k = blockIdx.x * 256 + threadIdx.x;
  if (k >= NKEY) return;                  // whole waves exit; 4-groups stay intact
  int r = k & 3;
  int beg = iclamp(offs[k], 0, N_EDGES);
  int end = iclamp(offs[k + 1], beg, N_EDGES);
  float a0 = 0.f, a1 = 0.f, b0 = 0.f, b1 = 0.f, c0 = 0.f, c1 = 0.f, d0 = 0.f, d1 = 0.f;
  int i = beg;
  for (; i + 4 <= end; i += 4){
    int s0 = iclamp(ssrc[i],     0, N_NODES - 1);
    int s1 = iclamp(ssrc[i + 1], 0, N_NODES - 1);
    int s2 = iclamp(ssrc[i + 2], 0, N_NODES - 1);
    int s3 = iclamp(ssrc[i + 3], 0, N_NODES - 1);
    float2 v0 = *(const float2*)(zt + (size_t)s0 * 8 + r * 2);
    float2 v1 = *(const float2*)(zt + (size_t)s1 * 8 + r * 2);
    float2 v2 = *(const float2*)(zt + (size_t)s2 * 8 + r * 2);
    float2 v3 = *(const float2*)(zt + (size_t)s3 * 8 + r * 2);
    a0 += v0.x; a1 += v0.y;
    b0 += v1.x; b1 += v1.y;
    c0 += v2.x; c1 += v2.y;
    d0 += v3.x; d1 += v3.y;
  }
  for (; i < end; i++){
    int s = iclamp(ssrc[i], 0, N_NODES - 1);
    float2 v = *(const float2*)(zt + (size_t)s * 8 + r * 2);
    a0 += v.x; a1 += v.y;
  }
  int cnt = end - beg;
  float sc = (cnt > 0) ? 1.0f / (float)cnt : 0.0f;
  float dA = (a0 + b0 + c0 + d0) * sc;
  float dB = (a1 + b1 + c1 + d1) * sc;
  // sum the 4 relations (4 consecutive lanes of this wave)
  dA += __shfl_xor(dA, 1); dB += __shfl_xor(dB, 1);
  dA += __shfl_xor(dA, 2); dB += __shfl_xor(dB, 2);
  if (r == 0){
    int n = k >> 2;
    float mx = fmaxf(dA, dB);
    float e0 = __expf(dA - mx), e1 = __expf(dB - mx);
    float inv = 1.0f / (e0 + e1);
    *(float2*)(out + 2 * n) = (float2){e0 * inv, e1 * inv};            // softmax [N,2]
    *(float2*)(out + 2 * N_NODES + 2 * n) = (float2){dA, dB};          // logits  [N,2]
  }
}

// ---------------- launch ----------------

extern "C" void kernel_launch(void* const* d_in, const int* in_sizes, int n_in,
                              void* d_out, int out_size, void* d_ws, size_t ws_size,
                              hipStream_t stream){
  const float* x  = (const float*)d_in[0];
  const int* ei   = (const int*)d_in[1];
  const int* et   = (const int*)d_in[2];
  const float* W1 = (const float*)d_in[3];
  const float* W2 = (const float*)d_in[4];
  const float* W3 = (const float*)d_in[5];
  float* out = (float*)d_out;
  const int* src = ei;
  const int* dst = ei + N_EDGES;

  // workspace layout: ~61 MB total
  char* p = (char*)d_ws;
  auto alloc = [&](size_t bytes) -> char* {
    char* q = p; p += (bytes + 63) & ~(size_t)63; return q;
  };
  int* counts = (int*)alloc((size_t)NKEY * 4);          // reused as cursor
  int* cursor = counts;
  int* offs   = (int*)alloc((size_t)(NKEY + 1) * 4);
  int* bsums  = (int*)alloc(1024 * 4);
  int* ssrc   = (int*)alloc((size_t)N_EDGES * 4);
  char* zrow  = alloc(256);                             // 256 B zero row for masked lanes
  unsigned short* Bt = (unsigned short*)alloc((size_t)DDIM * KDIM * 2);
  unsigned short* h1 = (unsigned short*)alloc((size_t)N_NODES * DDIM * 2);
  unsigned short* h2 = (unsigned short*)alloc((size_t)N_NODES * DDIM * 2);
  unsigned* xb = (unsigned*)h2;   // x-as-bf16 lives in h2's slot (dead until layer-2 output)
  float* zt = (float*)h1;         // z table aliases h1 (dead after layer-2 reads it)

  // sort edges by (dst, relation)
  hipMemsetAsync(counts, 0, (size_t)NKEY * 4, stream);
  hipMemsetAsync(zrow, 0, 256, stream);
  hist_kernel<<<N_EDGES / 256, 256, 0, stream>>>(dst, et, counts);
  int nb = (NKEY + 1023) / 1024;  // 391
  scan_local<<<nb, 1024, 0, stream>>>(counts, offs, bsums, NKEY);
  scan_sums<<<1, 1024, 0, stream>>>(bsums, nb);
  scan_add<<<nb, 1024, 0, stream>>>(offs, cursor, bsums, NKEY, N_EDGES);
  scatter_kernel<<<N_EDGES / 256, 256, 0, stream>>>(src, dst, et, cursor, ssrc);

  int fgrid = (N_NODES + 63) / 64;  // 1563

  // layer 1: x -> packed bf16, agg -> @W1 -> tanh -> h1
  convert_x<<<(N_NODES * 64) / 256, 256, 0, stream>>>(x, xb);
  transpose_w<<<(DDIM * KDIM) / 256, 256, 0, stream>>>(W1, Bt);
  fused_layer<<<fgrid, 256, 0, stream>>>(xb, ssrc, offs, (const __bf16*)Bt, zrow, h1);
  // layer 2: h1 -> h2 (xb dead from here on)
  transpose_w<<<(DDIM * KDIM) / 256, 256, 0, stream>>>(W2, Bt);
  fused_layer<<<fgrid, 256, 0, stream>>>((const unsigned*)h1, ssrc, offs, (const __bf16*)Bt, zrow, h2);
  // layer 3 head: z = h2 @ W3 per relation (8 f32/node), then 8 B/edge gather + softmax
  compute_z<<<N_NODES / 4, 256, 0, stream>>>((const unsigned*)h2, W3, zt);
  fused_head2<<<(NKEY + 255) / 256, 256, 0, stream>>>(zt, ssrc, offs, out);
}

// Round 11
// 767.136 us; speedup vs baseline: 3.6163x; 1.0407x over previous
//
#include <hip/hip_runtime.h>
#include <math.h>

#define N_NODES 100000
#define N_EDGES 1600000
#define RREL 4
#define DDIM 128
#define KDIM 512      // RREL*DDIM
#define NKEY 400000   // N_NODES*RREL

typedef __bf16 bf16x8 __attribute__((ext_vector_type(8)));
typedef float f32x4 __attribute__((ext_vector_type(4)));

__device__ __forceinline__ float bflo(unsigned u){ return __builtin_bit_cast(float, u << 16); }
__device__ __forceinline__ float bfhi(unsigned u){ return __builtin_bit_cast(float, u & 0xffff0000u); }
__device__ __forceinline__ unsigned f2bf(float f){
  unsigned u = __builtin_bit_cast(unsigned, f);
  return (u + 0x7fffu + ((u >> 16) & 1u)) >> 16;   // RNE, finite inputs
}
__device__ __forceinline__ int iclamp(int v, int lo, int hi){
  return v < lo ? lo : (v > hi ? hi : v);
}

#define GLL(gp, lp) __builtin_amdgcn_global_load_lds( \
    (const __attribute__((address_space(1))) void*)(gp), \
    (__attribute__((address_space(3))) void*)(lp), 16, 0, 0)

// ---------------- counting sort of edges by key = dst*4 + et ----------------

__global__ void hist_kernel(const int* __restrict__ dst, const int* __restrict__ et,
                            int* __restrict__ counts){
  int e = blockIdx.x * 256 + threadIdx.x;
  int key = iclamp(dst[e] * RREL + et[e], 0, NKEY - 1);
  atomicAdd(&counts[key], 1);
}

__global__ void scan_local(const int* __restrict__ in, int* __restrict__ out,
                           int* __restrict__ bsums, int K){
  __shared__ int s[1024];
  int t = threadIdx.x;
  int i = blockIdx.x * 1024 + t;
  int v = (i < K) ? in[i] : 0;
  s[t] = v; __syncthreads();
  for (int off = 1; off < 1024; off <<= 1){
    int x = (t >= off) ? s[t - off] : 0;
    __syncthreads();
    s[t] += x;
    __syncthreads();
  }
  if (i < K) out[i] = s[t] - v;           // exclusive within block
  if (t == 1023) bsums[blockIdx.x] = s[t];
}

__global__ void scan_sums(int* __restrict__ b, int nb){
  __shared__ int s[1024];
  int t = threadIdx.x;
  int v = (t < nb) ? b[t] : 0;
  s[t] = v; __syncthreads();
  for (int off = 1; off < 1024; off <<= 1){
    int x = (t >= off) ? s[t - off] : 0;
    __syncthreads();
    s[t] += x;
    __syncthreads();
  }
  if (t < nb) b[t] = s[t] - v;            // exclusive block prefix
}

__global__ void scan_add(int* __restrict__ out, int* __restrict__ cursor,
                         const int* __restrict__ bsums, int K, int total){
  int t = threadIdx.x;
  int i = blockIdx.x * 1024 + t;
  if (i < K){
    int v = out[i] + bsums[blockIdx.x];
    out[i] = v;
    cursor[i] = v;
  }
  if (i == 0) out[K] = total;
}

__global__ void scatter_kernel(const int* __restrict__ src, const int* __restrict__ dst,
                               const int* __restrict__ et, int* __restrict__ cursor,
                               int* __restrict__ ssrc){
  int e = blockIdx.x * 256 + threadIdx.x;
  int key = iclamp(dst[e] * RREL + et[e], 0, NKEY - 1);
  int p = atomicAdd(&cursor[key], 1);
  p = iclamp(p, 0, N_EDGES - 1);
  ssrc[p] = iclamp(src[e], 0, N_NODES - 1);
}

// ---------------- x (f32 [N,128]) -> packed bf16 pairs [N,64] uints ----------------

__global__ void convert_x(const float* __restrict__ x, unsigned* __restrict__ xb){
  int i = blockIdx.x * 256 + threadIdx.x;      // over N*64
  float2 v = *(const float2*)(x + (size_t)i * 2);
  xb[i] = f2bf(v.x) | (f2bf(v.y) << 16);
}

// ---------------- W (f32 [512][128]) -> Bt bf16 [128][512] ----------------

__global__ void transpose_w(const float* __restrict__ W, unsigned short* __restrict__ Bt){
  int idx = blockIdx.x * 256 + threadIdx.x;    // 65536
  int k = idx >> 7, n = idx & 127;
  Bt[n * KDIM + k] = (unsigned short)f2bf(W[idx]);
}

// ---------------- fused layer: LDS-staged gather -> mean -> @W -> tanh ----------------
// r10 bug fixed: idx loads for stage i+1 were issued right before the GLLs that consume
// them -> in-order vmcnt forced a full drain (vmcnt(0)) before every GLL issue, exposing
// idx latency AND killing the double buffer (in-flight fell back to the r0 level; same
// 200us). Now indices are prefetched ONE FULL ITERATION ahead: per iteration —
// vmcnt(0) (drains stage-i GLLs + idx_{i+1}, both ~700cy old -> idx wait is free) ->
// issue GLL_{i+1} from registers -> issue idx_{i+2} -> accumulate stage i. GLLs fly
// through the whole accumulate: steady 64 lines/wave at ~100% duty vs bursty 50%.

__global__ __launch_bounds__(256) void fused_layer(const unsigned* __restrict__ hin,
                                                   const int* __restrict__ ssrc,
                                                   const int* __restrict__ offs,
                                                   const __bf16* __restrict__ Bt,
                                                   const char* __restrict__ zrow,
                                                   unsigned short* __restrict__ hout){
  __shared__ uint4 smem4[2048];          // 4 waves x 2 bufs x 16 rows x 256 B = 32 KB

  int tid = threadIdx.x;
  int w = tid >> 6, lane = tid & 63;
  int l15 = lane & 15, quad = lane >> 4;
  int n0w = blockIdx.x * 64 + w * 16;
  int n = n0w + l15;                     // this lane's node
  int valid = (n < N_NODES);
  const char* hinB = (const char*)hin;
  uint4* lw = &smem4[w << 9];            // this wave's 512-uint4 region

  f32x4 accC[8];
  #pragma unroll
  for (int tc = 0; tc < 8; tc++) accC[tc] = (f32x4){0.f, 0.f, 0.f, 0.f};

  // per-lane staging constants: instr j serves row g = j*4+quad at position p = l15;
  // source chunk q = p ^ g (inverse of the read-side swizzle)
  int q0 = (l15 ^ (quad)) * 16;
  int q1 = (l15 ^ (4 + quad)) * 16;
  int q2 = (l15 ^ (8 + quad)) * 16;
  int q3 = (l15 ^ (12 + quad)) * 16;

  #pragma unroll
  for (int r = 0; r < RREL; r++){
    int ob = valid ? (n * 4 + r) : 0;
    int beg = iclamp(offs[ob], 0, N_EDGES);
    int end = iclamp(offs[ob + 1], beg, N_EDGES);
    if (!valid){ beg = 0; end = 0; }
    int deg = end - beg;

    int trip = deg;                      // wave-uniform step count = max degree
    #pragma unroll
    for (int k = 1; k < 64; k <<= 1){
      int o = __shfl_xor(trip, k);
      trip = trip > o ? trip : o;
    }

    float ac[32];
    #pragma unroll
    for (int j = 0; j < 32; j++) ac[j] = 0.f;

    if (trip > 0){
      // per-instruction node ranges: row g = j*4+quad -> lane g holds that node's beg/end
      int bg0 = __shfl(beg, quad),      eg0 = __shfl(end, quad);
      int bg1 = __shfl(beg, 4 + quad),  eg1 = __shfl(end, 4 + quad);
      int bg2 = __shfl(beg, 8 + quad),  eg2 = __shfl(end, 8 + quad);
      int bg3 = __shfl(beg, 12 + quad), eg3 = __shfl(end, 12 + quad);

      // prologue: idx(step 0) -> GLL stage 0 into buf 0 -> idx(step 1) into regs
      int svA0 = ssrc[iclamp(bg0, 0, N_EDGES - 1)];
      int svA1 = ssrc[iclamp(bg1, 0, N_EDGES - 1)];
      int svA2 = ssrc[iclamp(bg2, 0, N_EDGES - 1)];
      int svA3 = ssrc[iclamp(bg3, 0, N_EDGES - 1)];
      {
        const char* a0 = (0 < eg0 - bg0) ? hinB + (size_t)(unsigned)svA0 * 256 + q0 : zrow + q0;
        const char* a1 = (0 < eg1 - bg1) ? hinB + (size_t)(unsigned)svA1 * 256 + q1 : zrow + q1;
        const char* a2 = (0 < eg2 - bg2) ? hinB + (size_t)(unsigned)svA2 * 256 + q2 : zrow + q2;
        const char* a3 = (0 < eg3 - bg3) ? hinB + (size_t)(unsigned)svA3 * 256 + q3 : zrow + q3;
        GLL(a0, lw + 0);
        GLL(a1, lw + 64);
        GLL(a2, lw + 128);
        GLL(a3, lw + 192);
      }
      svA0 = ssrc[iclamp(bg0 + 1, 0, N_EDGES - 1)];
      svA1 = ssrc[iclamp(bg1 + 1, 0, N_EDGES - 1)];
      svA2 = ssrc[iclamp(bg2 + 1, 0, N_EDGES - 1)];
      svA3 = ssrc[iclamp(bg3 + 1, 0, N_EDGES - 1)];

      for (int i = 0; i < trip; i++){
        int b = i & 1;
        // drain stage-i GLLs (and idx_{i+1}, issued a full iteration ago -> free)
        asm volatile("s_waitcnt vmcnt(0)" ::: "memory");
        __builtin_amdgcn_sched_barrier(0);
        if (i + 1 < trip){
          // issue GLL stage i+1 from registers (no wait needed)
          uint4* db = lw + ((b ^ 1) << 8);
          const char* a0 = (i + 1 < eg0 - bg0) ? hinB + (size_t)(unsigned)svA0 * 256 + q0 : zrow + q0;
          const char* a1 = (i + 1 < eg1 - bg1) ? hinB + (size_t)(unsigned)svA1 * 256 + q1 : zrow + q1;
          const char* a2 = (i + 1 < eg2 - bg2) ? hinB + (size_t)(unsigned)svA2 * 256 + q2 : zrow + q2;
          const char* a3 = (i + 1 < eg3 - bg3) ? hinB + (size_t)(unsigned)svA3 * 256 + q3 : zrow + q3;
          GLL(a0, db + 0);
          GLL(a1, db + 64);
          GLL(a2, db + 128);
          GLL(a3, db + 192);
          // prefetch idx for stage i+2 (lands by the next iteration's drain)
          svA0 = ssrc[iclamp(bg0 + i + 2, 0, N_EDGES - 1)];
          svA1 = ssrc[iclamp(bg1 + i + 2, 0, N_EDGES - 1)];
          svA2 = ssrc[iclamp(bg2 + i + 2, 0, N_EDGES - 1)];
          svA3 = ssrc[iclamp(bg3 + i + 2, 0, N_EDGES - 1)];
        }

        // accumulate step i from buf b: row l15, chunk (j*4+quad)^l15 (swizzled read)
        const uint4* rb = lw + (b << 8) + (l15 << 4);
        uint4 u0 = rb[(0 * 4 + quad) ^ l15];
        uint4 u1 = rb[(1 * 4 + quad) ^ l15];
        uint4 u2 = rb[(2 * 4 + quad) ^ l15];
        uint4 u3 = rb[(3 * 4 + quad) ^ l15];
        ac[ 0] += bflo(u0.x); ac[ 1] += bfhi(u0.x); ac[ 2] += bflo(u0.y); ac[ 3] += bfhi(u0.y);
        ac[ 4] += bflo(u0.z); ac[ 5] += bfhi(u0.z); ac[ 6] += bflo(u0.w); ac[ 7] += bfhi(u0.w);
        ac[ 8] += bflo(u1.x); ac[ 9] += bfhi(u1.x); ac[10] += bflo(u1.y); ac[11] += bfhi(u1.y);
        ac[12] += bflo(u1.z); ac[13] += bfhi(u1.z); ac[14] += bflo(u1.w); ac[15] += bfhi(u1.w);
        ac[16] += bflo(u2.x); ac[17] += bfhi(u2.x); ac[18] += bflo(u2.y); ac[19] += bfhi(u2.y);
        ac[20] += bflo(u2.z); ac[21] += bfhi(u2.z); ac[22] += bflo(u2.w); ac[23] += bfhi(u2.w);
        ac[24] += bflo(u3.x); ac[25] += bfhi(u3.x); ac[26] += bflo(u3.y); ac[27] += bfhi(u3.y);
        ac[28] += bflo(u3.z); ac[29] += bfhi(u3.z); ac[30] += bflo(u3.w); ac[31] += bfhi(u3.w);
      }
    }

    float sc = (deg > 0) ? 1.0f / (float)deg : 0.0f;

    // 4 MFMA K-steps for this relation; A-frag packed from ac (unchanged, verified)
    #pragma unroll
    for (int s = 0; s < 4; s++){
      uint4 pv;
      pv.x = f2bf(ac[s * 8 + 0] * sc) | (f2bf(ac[s * 8 + 1] * sc) << 16);
      pv.y = f2bf(ac[s * 8 + 2] * sc) | (f2bf(ac[s * 8 + 3] * sc) << 16);
      pv.z = f2bf(ac[s * 8 + 4] * sc) | (f2bf(ac[s * 8 + 5] * sc) << 16);
      pv.w = f2bf(ac[s * 8 + 6] * sc) | (f2bf(ac[s * 8 + 7] * sc) << 16);
      bf16x8 af = __builtin_bit_cast(bf16x8, pv);
      const __bf16* bbase = Bt + r * 128 + s * 32 + quad * 8;
      #pragma unroll
      for (int tc = 0; tc < 8; tc++){
        bf16x8 bfr = *(const bf16x8*)(bbase + (size_t)(tc * 16 + l15) * KDIM);
        accC[tc] = __builtin_amdgcn_mfma_f32_16x16x32_bf16(af, bfr, accC[tc], 0, 0, 0);
      }
    }
  }

  // epilogue: tanh, store bf16. C layout: col=l15, row=quad*4+reg
  #pragma unroll
  for (int tc = 0; tc < 8; tc++){
    #pragma unroll
    for (int reg = 0; reg < 4; reg++){
      int n2 = n0w + quad * 4 + reg;
      if (n2 < N_NODES){
        float v = tanhf(accC[tc][reg]);
        hout[(size_t)n2 * 128 + tc * 16 + l15] = (unsigned short)f2bf(v);
      }
    }
  }
}

// ---------------- z precompute: z[n][r][2] = h2[n] . W3_r  (head linearity) ----------------

__global__ void compute_z(const unsigned* __restrict__ h2, const float* __restrict__ W3f,
                          float* __restrict__ zt){
  int n = blockIdx.x * 4 + (threadIdx.x >> 6);
  int lane = threadIdx.x & 63;
  unsigned u = h2[(size_t)n * 64 + lane];
  float a = bflo(u), b = bfhi(u);
  float p[8];
  #pragma unroll
  for (int r = 0; r < RREL; r++){
    float4 wv = *(const float4*)(W3f + r * 256 + lane * 4);
    p[r * 2]     = a * wv.x + b * wv.z;
    p[r * 2 + 1] = a * wv.y + b * wv.w;
  }
  #pragma unroll
  for (int m = 32; m >= 1; m >>= 1){
    #pragma unroll
    for (int j = 0; j < 8; j++) p[j] += __shfl_xor(p[j], m);
  }
  if (lane == 0){
    *(float4*)(zt + (size_t)n * 8)     = (float4){p[0], p[1], p[2], p[3]};
    *(float4*)(zt + (size_t)n * 8 + 4) = (float4){p[4], p[5], p[6], p[7]};
  }
}

// ---------------- head: thread per (node,rel) key; mean of z[src,rel] -> reduce -> softmax ----

__global__ void fused_head2(const float* __restrict__ zt,
                            const int* __restrict__ ssrc,
                            const int* __restrict__ offs,
                            float* __restrict__ out){
  int k = blockIdx.x * 256 + threadIdx.x;
  if (k >= NKEY) return;                  // whole waves exit; 4-groups stay intact
  int r = k & 3;
  int beg = iclamp(offs[k], 0, N_EDGES);
  int end = iclamp(offs[k + 1], beg, N_EDGES);
  float a0 = 0.f, a1 = 0.f, b0 = 0.f, b1 = 0.f, c0 = 0.f, c1 = 0.f, d0 = 0.f, d1 = 0.f;
  int i = beg;
  for (; i + 4 <= end; i += 4){
    int s0 = iclamp(ssrc[i],     0, N_NODES - 1);
    int s1 = iclamp(ssrc[i + 1], 0, N_NODES - 1);
    int s2 = iclamp(ssrc[i + 2], 0, N_NODES - 1);
    int s3 = iclamp(ssrc[i + 3], 0, N_NODES - 1);
    float2 v0 = *(const float2*)(zt + (size_t)s0 * 8 + r * 2);
    float2 v1 = *(const float2*)(zt + (size_t)s1 * 8 + r * 2);
    float2 v2 = *(const float2*)(zt + (size_t)s2 * 8 + r * 2);
    float2 v3 = *(const float2*)(zt + (size_t)s3 * 8 + r * 2);
    a0 += v0.x; a1 += v0.y;
    b0 += v1.x; b1 += v1.y;
    c0 += v2.x; c1 += v2.y;
    d0 += v3.x; d1 += v3.y;
  }
  for (; i < end; i++){
    int s = iclamp(ssrc[i], 0, N_NODES - 1);
    float2 v = *(const float2*)(zt + (size_t)s * 8 + r * 2);
    a0 += v.x; a1 += v.y;
  }
  int cnt = end - beg;
  float sc = (cnt > 0) ? 1.0f / (float)cnt : 0.0f;
  float dA = (a0 + b0 + c0 + d0) * sc;
  float dB = (a1 + b1 + c1 + d1) * sc;
  // sum the 4 relations (4 consecutive lanes of this wave)
  dA += __shfl_xor(dA, 1); dB += __shfl_xor(dB, 1);
  dA += __shfl_xor(dA, 2); dB += __shfl_xor(dB, 2);
  if (r == 0){
    int n = k >> 2;
    float mx = fmaxf(dA, dB);
    float e0 = __expf(dA - mx), e1 = __expf(dB - mx);
    float inv = 1.0f / (e0 + e1);
    *(float2*)(out + 2 * n) = (float2){e0 * inv, e1 * inv};            // softmax [N,2]
    *(float2*)(out + 2 * N_NODES + 2 * n) = (float2){dA, dB};          // logits  [N,2]
  }
}

// ---------------- launch ----------------

extern "C" void kernel_launch(void* const* d_in, const int* in_sizes, int n_in,
                              void* d_out, int out_size, void* d_ws, size_t ws_size,
                              hipStream_t stream){
  const float* x  = (const float*)d_in[0];
  const int* ei   = (const int*)d_in[1];
  const int* et   = (const int*)d_in[2];
  const float* W1 = (const float*)d_in[3];
  const float* W2 = (const float*)d_in[4];
  const float* W3 = (const float*)d_in[5];
  float* out = (float*)d_out;
  const int* src = ei;
  const int* dst = ei + N_EDGES;

  // workspace layout: ~61 MB total
  char* p = (char*)d_ws;
  auto alloc = [&](size_t bytes) -> char* {
    char* q = p; p += (bytes + 63) & ~(size_t)63; return q;
  };
  int* counts = (int*)alloc((size_t)NKEY * 4);          // reused as cursor
  int* cursor = counts;
  int* offs   = (int*)alloc((size_t)(NKEY + 1) * 4);
  int* bsums  = (int*)alloc(1024 * 4);
  int* ssrc   = (int*)alloc((size_t)N_EDGES * 4);
  char* zrow  = alloc(256);                             // 256 B zero row for masked lanes
  unsigned short* Bt = (unsigned short*)alloc((size_t)DDIM * KDIM * 2);
  unsigned short* h1 = (unsigned short*)alloc((size_t)N_NODES * DDIM * 2);
  unsigned short* h2 = (unsigned short*)alloc((size_t)N_NODES * DDIM * 2);
  unsigned* xb = (unsigned*)h2;   // x-as-bf16 lives in h2's slot (dead until layer-2 output)
  float* zt = (float*)h1;         // z table aliases h1 (dead after layer-2 reads it)

  // sort edges by (dst, relation)
  hipMemsetAsync(counts, 0, (size_t)NKEY * 4, stream);
  hipMemsetAsync(zrow, 0, 256, stream);
  hist_kernel<<<N_EDGES / 256, 256, 0, stream>>>(dst, et, counts);
  int nb = (NKEY + 1023) / 1024;  // 391
  scan_local<<<nb, 1024, 0, stream>>>(counts, offs, bsums, NKEY);
  scan_sums<<<1, 1024, 0, stream>>>(bsums, nb);
  scan_add<<<nb, 1024, 0, stream>>>(offs, cursor, bsums, NKEY, N_EDGES);
  scatter_kernel<<<N_EDGES / 256, 256, 0, stream>>>(src, dst, et, cursor, ssrc);

  int fgrid = (N_NODES + 63) / 64;  // 1563

  // layer 1: x -> packed bf16, agg -> @W1 -> tanh -> h1
  convert_x<<<(N_NODES * 64) / 256, 256, 0, stream>>>(x, xb);
  transpose_w<<<(DDIM * KDIM) / 256, 256, 0, stream>>>(W1, Bt);
  fused_layer<<<fgrid, 256, 0, stream>>>(xb, ssrc, offs, (const __bf16*)Bt, zrow, h1);
  // layer 2: h1 -> h2 (xb dead from here on)
  transpose_w<<<(DDIM * KDIM) / 256, 256, 0, stream>>>(W2, Bt);
  fused_layer<<<fgrid, 256, 0, stream>>>((const unsigned*)h1, ssrc, offs, (const __bf16*)Bt, zrow, h2);
  // layer 3 head: z = h2 @ W3 per relation (8 f32/node), then 8 B/edge gather + softmax
  compute_z<<<N_NODES / 4, 256, 0, stream>>>((const unsigned*)h2, W3, zt);
  fused_head2<<<(NKEY + 255) / 256, 256, 0, stream>>>(zt, ssrc, offs, out);
}

// Round 12
// 751.010 us; speedup vs baseline: 3.6940x; 1.0215x over previous
//
#include <hip/hip_runtime.h>
#include <math.h>

#define N_NODES 100000
#define N_EDGES 1600000
#define RREL 4
#define DDIM 128
#define KDIM 512      // RREL*DDIM
#define NKEY 400000   // N_NODES*RREL

// mega_prep block ranges
#define HB 6250       // hist blocks
#define CB 25000      // convert_x blocks
#define TB 256        // transpose blocks (each)

typedef __bf16 bf16x8 __attribute__((ext_vector_type(8)));
typedef float f32x4 __attribute__((ext_vector_type(4)));

__device__ __forceinline__ float bflo(unsigned u){ return __builtin_bit_cast(float, u << 16); }
__device__ __forceinline__ float bfhi(unsigned u){ return __builtin_bit_cast(float, u & 0xffff0000u); }
__device__ __forceinline__ unsigned f2bf(float f){
  unsigned u = __builtin_bit_cast(unsigned, f);
  return (u + 0x7fffu + ((u >> 16) & 1u)) >> 16;   // RNE, finite inputs
}
__device__ __forceinline__ int iclamp(int v, int lo, int hi){
  return v < lo ? lo : (v > hi ? hi : v);
}

#define GLL(gp, lp) __builtin_amdgcn_global_load_lds( \
    (const __attribute__((address_space(1))) void*)(gp), \
    (__attribute__((address_space(3))) void*)(lp), 16, 0, 0)

// ---------------- mega prep: hist + convert_x + transpose W1/W2 (independent work,
// fused by block range to cut 3 dispatches of launch overhead) ----------------

__global__ void mega_prep(const int* __restrict__ dst, const int* __restrict__ et,
                          int* __restrict__ counts,
                          const float* __restrict__ x, unsigned* __restrict__ xb,
                          const float* __restrict__ W1, unsigned short* __restrict__ Bt1,
                          const float* __restrict__ W2, unsigned short* __restrict__ Bt2){
  int b = blockIdx.x, t = threadIdx.x;
  if (b < HB){
    int e = b * 256 + t;
    int key = iclamp(dst[e] * RREL + et[e], 0, NKEY - 1);
    atomicAdd(&counts[key], 1);
  } else if (b < HB + CB){
    int i = (b - HB) * 256 + t;                 // over N*64
    float2 v = *(const float2*)(x + (size_t)i * 2);
    xb[i] = f2bf(v.x) | (f2bf(v.y) << 16);
  } else if (b < HB + CB + TB){
    int idx = (b - HB - CB) * 256 + t;          // 65536
    int k = idx >> 7, n = idx & 127;
    Bt1[n * KDIM + k] = (unsigned short)f2bf(W1[idx]);
  } else {
    int idx = (b - HB - CB - TB) * 256 + t;
    int k = idx >> 7, n = idx & 127;
    Bt2[n * KDIM + k] = (unsigned short)f2bf(W2[idx]);
  }
}

// ---------------- scan: 2 dispatches (local scan; add with in-block bsums reduce) ----

__global__ void scan_local(const int* __restrict__ in, int* __restrict__ out,
                           int* __restrict__ bsums, int K){
  __shared__ int s[1024];
  int t = threadIdx.x;
  int i = blockIdx.x * 1024 + t;
  int v = (i < K) ? in[i] : 0;
  s[t] = v; __syncthreads();
  for (int off = 1; off < 1024; off <<= 1){
    int x = (t >= off) ? s[t - off] : 0;
    __syncthreads();
    s[t] += x;
    __syncthreads();
  }
  if (i < K) out[i] = s[t] - v;           // exclusive within block
  if (t == 1023) bsums[blockIdx.x] = s[t];
}

// absorbs scan_sums: wave 0 of each block reduces bsums[0..bid) itself (<=7 chunks of 64)
__global__ void scan_add2(int* __restrict__ out, int* __restrict__ cursor,
                          const int* __restrict__ bsums, int K, int nb, int total_unused){
  __shared__ int base_s;
  int t = threadIdx.x, bid = blockIdx.x;
  if (t < 64){
    int s = 0;
    for (int j = t; j < bid; j += 64) s += bsums[j];
    #pragma unroll
    for (int m = 32; m >= 1; m >>= 1) s += __shfl_xor(s, m);
    if (t == 0) base_s = s;
  }
  __syncthreads();
  int base = base_s;
  int i = bid * 1024 + t;
  if (i < K){
    int v = out[i] + base;
    out[i] = v;
    cursor[i] = v;
  }
  if (bid == 0 && t < 64){
    int s = 0;
    for (int j = t; j < nb; j += 64) s += bsums[j];
    #pragma unroll
    for (int m = 32; m >= 1; m >>= 1) s += __shfl_xor(s, m);
    if (t == 0) out[K] = s;               // total
  }
}

__global__ void scatter_kernel(const int* __restrict__ src, const int* __restrict__ dst,
                               const int* __restrict__ et, int* __restrict__ cursor,
                               int* __restrict__ ssrc){
  int e = blockIdx.x * 256 + threadIdx.x;
  int key = iclamp(dst[e] * RREL + et[e], 0, NKEY - 1);
  int p = atomicAdd(&cursor[key], 1);
  p = iclamp(p, 0, N_EDGES - 1);
  ssrc[p] = iclamp(src[e], 0, N_NODES - 1);
}

// ---------------- fused layer: LDS-staged gather -> mean -> @W -> tanh ----------------
// (r11 structure, unchanged — at the per-CU line-service wall: 4 independent structures
// all converge to ~200us/layer; 6.4M lines / 200us = ~36 lines in flight per CU at
// ~700cy latency = TCP MSHR cap. Steady GLL double-buffer + idx prefetched one full
// iteration ahead; vmcnt(0) drains only ~700cy-old ops.)

__global__ __launch_bounds__(256) void fused_layer(const unsigned* __restrict__ hin,
                                                   const int* __restrict__ ssrc,
                                                   const int* __restrict__ offs,
                                                   const __bf16* __restrict__ Bt,
                                                   const char* __restrict__ zrow,
                                                   unsigned short* __restrict__ hout){
  __shared__ uint4 smem4[2048];          // 4 waves x 2 bufs x 16 rows x 256 B = 32 KB

  int tid = threadIdx.x;
  int w = tid >> 6, lane = tid & 63;
  int l15 = lane & 15, quad = lane >> 4;
  int n0w = blockIdx.x * 64 + w * 16;
  int n = n0w + l15;                     // this lane's node
  int valid = (n < N_NODES);
  const char* hinB = (const char*)hin;
  uint4* lw = &smem4[w << 9];            // this wave's 512-uint4 region

  f32x4 accC[8];
  #pragma unroll
  for (int tc = 0; tc < 8; tc++) accC[tc] = (f32x4){0.f, 0.f, 0.f, 0.f};

  int q0 = (l15 ^ (quad)) * 16;
  int q1 = (l15 ^ (4 + quad)) * 16;
  int q2 = (l15 ^ (8 + quad)) * 16;
  int q3 = (l15 ^ (12 + quad)) * 16;

  #pragma unroll
  for (int r = 0; r < RREL; r++){
    int ob = valid ? (n * 4 + r) : 0;
    int beg = iclamp(offs[ob], 0, N_EDGES);
    int end = iclamp(offs[ob + 1], beg, N_EDGES);
    if (!valid){ beg = 0; end = 0; }
    int deg = end - beg;

    int trip = deg;                      // wave-uniform step count = max degree
    #pragma unroll
    for (int k = 1; k < 64; k <<= 1){
      int o = __shfl_xor(trip, k);
      trip = trip > o ? trip : o;
    }

    float ac[32];
    #pragma unroll
    for (int j = 0; j < 32; j++) ac[j] = 0.f;

    if (trip > 0){
      int bg0 = __shfl(beg, quad),      eg0 = __shfl(end, quad);
      int bg1 = __shfl(beg, 4 + quad),  eg1 = __shfl(end, 4 + quad);
      int bg2 = __shfl(beg, 8 + quad),  eg2 = __shfl(end, 8 + quad);
      int bg3 = __shfl(beg, 12 + quad), eg3 = __shfl(end, 12 + quad);

      int svA0 = ssrc[iclamp(bg0, 0, N_EDGES - 1)];
      int svA1 = ssrc[iclamp(bg1, 0, N_EDGES - 1)];
      int svA2 = ssrc[iclamp(bg2, 0, N_EDGES - 1)];
      int svA3 = ssrc[iclamp(bg3, 0, N_EDGES - 1)];
      {
        const char* a0 = (0 < eg0 - bg0) ? hinB + (size_t)(unsigned)svA0 * 256 + q0 : zrow + q0;
        const char* a1 = (0 < eg1 - bg1) ? hinB + (size_t)(unsigned)svA1 * 256 + q1 : zrow + q1;
        const char* a2 = (0 < eg2 - bg2) ? hinB + (size_t)(unsigned)svA2 * 256 + q2 : zrow + q2;
        const char* a3 = (0 < eg3 - bg3) ? hinB + (size_t)(unsigned)svA3 * 256 + q3 : zrow + q3;
        GLL(a0, lw + 0);
        GLL(a1, lw + 64);
        GLL(a2, lw + 128);
        GLL(a3, lw + 192);
      }
      svA0 = ssrc[iclamp(bg0 + 1, 0, N_EDGES - 1)];
      svA1 = ssrc[iclamp(bg1 + 1, 0, N_EDGES - 1)];
      svA2 = ssrc[iclamp(bg2 + 1, 0, N_EDGES - 1)];
      svA3 = ssrc[iclamp(bg3 + 1, 0, N_EDGES - 1)];

      for (int i = 0; i < trip; i++){
        int b = i & 1;
        asm volatile("s_waitcnt vmcnt(0)" ::: "memory");
        __builtin_amdgcn_sched_barrier(0);
        if (i + 1 < trip){
          uint4* db = lw + ((b ^ 1) << 8);
          const char* a0 = (i + 1 < eg0 - bg0) ? hinB + (size_t)(unsigned)svA0 * 256 + q0 : zrow + q0;
          const char* a1 = (i + 1 < eg1 - bg1) ? hinB + (size_t)(unsigned)svA1 * 256 + q1 : zrow + q1;
          const char* a2 = (i + 1 < eg2 - bg2) ? hinB + (size_t)(unsigned)svA2 * 256 + q2 : zrow + q2;
          const char* a3 = (i + 1 < eg3 - bg3) ? hinB + (size_t)(unsigned)svA3 * 256 + q3 : zrow + q3;
          GLL(a0, db + 0);
          GLL(a1, db + 64);
          GLL(a2, db + 128);
          GLL(a3, db + 192);
          svA0 = ssrc[iclamp(bg0 + i + 2, 0, N_EDGES - 1)];
          svA1 = ssrc[iclamp(bg1 + i + 2, 0, N_EDGES - 1)];
          svA2 = ssrc[iclamp(bg2 + i + 2, 0, N_EDGES - 1)];
          svA3 = ssrc[iclamp(bg3 + i + 2, 0, N_EDGES - 1)];
        }

        const uint4* rb = lw + (b << 8) + (l15 << 4);
        uint4 u0 = rb[(0 * 4 + quad) ^ l15];
        uint4 u1 = rb[(1 * 4 + quad) ^ l15];
        uint4 u2 = rb[(2 * 4 + quad) ^ l15];
        uint4 u3 = rb[(3 * 4 + quad) ^ l15];
        ac[ 0] += bflo(u0.x); ac[ 1] += bfhi(u0.x); ac[ 2] += bflo(u0.y); ac[ 3] += bfhi(u0.y);
        ac[ 4] += bflo(u0.z); ac[ 5] += bfhi(u0.z); ac[ 6] += bflo(u0.w); ac[ 7] += bfhi(u0.w);
        ac[ 8] += bflo(u1.x); ac[ 9] += bfhi(u1.x); ac[10] += bflo(u1.y); ac[11] += bfhi(u1.y);
        ac[12] += bflo(u1.z); ac[13] += bfhi(u1.z); ac[14] += bflo(u1.w); ac[15] += bfhi(u1.w);
        ac[16] += bflo(u2.x); ac[17] += bfhi(u2.x); ac[18] += bflo(u2.y); ac[19] += bfhi(u2.y);
        ac[20] += bflo(u2.z); ac[21] += bfhi(u2.z); ac[22] += bflo(u2.w); ac[23] += bfhi(u2.w);
        ac[24] += bflo(u3.x); ac[25] += bfhi(u3.x); ac[26] += bflo(u3.y); ac[27] += bfhi(u3.y);
        ac[28] += bflo(u3.z); ac[29] += bfhi(u3.z); ac[30] += bflo(u3.w); ac[31] += bfhi(u3.w);
      }
    }

    float sc = (deg > 0) ? 1.0f / (float)deg : 0.0f;

    #pragma unroll
    for (int s = 0; s < 4; s++){
      uint4 pv;
      pv.x = f2bf(ac[s * 8 + 0] * sc) | (f2bf(ac[s * 8 + 1] * sc) << 16);
      pv.y = f2bf(ac[s * 8 + 2] * sc) | (f2bf(ac[s * 8 + 3] * sc) << 16);
      pv.z = f2bf(ac[s * 8 + 4] * sc) | (f2bf(ac[s * 8 + 5] * sc) << 16);
      pv.w = f2bf(ac[s * 8 + 6] * sc) | (f2bf(ac[s * 8 + 7] * sc) << 16);
      bf16x8 af = __builtin_bit_cast(bf16x8, pv);
      const __bf16* bbase = Bt + r * 128 + s * 32 + quad * 8;
      #pragma unroll
      for (int tc = 0; tc < 8; tc++){
        bf16x8 bfr = *(const bf16x8*)(bbase + (size_t)(tc * 16 + l15) * KDIM);
        accC[tc] = __builtin_amdgcn_mfma_f32_16x16x32_bf16(af, bfr, accC[tc], 0, 0, 0);
      }
    }
  }

  #pragma unroll
  for (int tc = 0; tc < 8; tc++){
    #pragma unroll
    for (int reg = 0; reg < 4; reg++){
      int n2 = n0w + quad * 4 + reg;
      if (n2 < N_NODES){
        float v = tanhf(accC[tc][reg]);
        hout[(size_t)n2 * 128 + tc * 16 + l15] = (unsigned short)f2bf(v);
      }
    }
  }
}

// ---------------- z precompute: z[n][r][2] = h2[n] . W3_r  (head linearity) ----------------

__global__ void compute_z(const unsigned* __restrict__ h2, const float* __restrict__ W3f,
                          float* __restrict__ zt){
  int n = blockIdx.x * 4 + (threadIdx.x >> 6);
  int lane = threadIdx.x & 63;
  unsigned u = h2[(size_t)n * 64 + lane];
  float a = bflo(u), b = bfhi(u);
  float p[8];
  #pragma unroll
  for (int r = 0; r < RREL; r++){
    float4 wv = *(const float4*)(W3f + r * 256 + lane * 4);
    p[r * 2]     = a * wv.x + b * wv.z;
    p[r * 2 + 1] = a * wv.y + b * wv.w;
  }
  #pragma unroll
  for (int m = 32; m >= 1; m >>= 1){
    #pragma unroll
    for (int j = 0; j < 8; j++) p[j] += __shfl_xor(p[j], m);
  }
  if (lane == 0){
    *(float4*)(zt + (size_t)n * 8)     = (float4){p[0], p[1], p[2], p[3]};
    *(float4*)(zt + (size_t)n * 8 + 4) = (float4){p[4], p[5], p[6], p[7]};
  }
}

// ---------------- head: thread per (node,rel) key; mean of z[src,rel] -> reduce -> softmax ----

__global__ void fused_head2(const float* __restrict__ zt,
                            const int* __restrict__ ssrc,
                            const int* __restrict__ offs,
                            float* __restrict__ out){
  int k = blockIdx.x * 256 + threadIdx.x;
  if (k >= NKEY) return;                  // whole waves exit; 4-groups stay intact
  int r = k & 3;
  int beg = iclamp(offs[k], 0, N_EDGES);
  int end = iclamp(offs[k + 1], beg, N_EDGES);
  float a0 = 0.f, a1 = 0.f, b0 = 0.f, b1 = 0.f, c0 = 0.f, c1 = 0.f, d0 = 0.f, d1 = 0.f;
  int i = beg;
  for (; i + 4 <= end; i += 4){
    int s0 = iclamp(ssrc[i],     0, N_NODES - 1);
    int s1 = iclamp(ssrc[i + 1], 0, N_NODES - 1);
    int s2 = iclamp(ssrc[i + 2], 0, N_NODES - 1);
    int s3 = iclamp(ssrc[i + 3], 0, N_NODES - 1);
    float2 v0 = *(const float2*)(zt + (size_t)s0 * 8 + r * 2);
    float2 v1 = *(const float2*)(zt + (size_t)s1 * 8 + r * 2);
    float2 v2 = *(const float2*)(zt + (size_t)s2 * 8 + r * 2);
    float2 v3 = *(const float2*)(zt + (size_t)s3 * 8 + r * 2);
    a0 += v0.x; a1 += v0.y;
    b0 += v1.x; b1 += v1.y;
    c0 += v2.x; c1 += v2.y;
    d0 += v3.x; d1 += v3.y;
  }
  for (; i < end; i++){
    int s = iclamp(ssrc[i], 0, N_NODES - 1);
    float2 v = *(const float2*)(zt + (size_t)s * 8 + r * 2);
    a0 += v.x; a1 += v.y;
  }
  int cnt = end - beg;
  float sc = (cnt > 0) ? 1.0f / (float)cnt : 0.0f;
  float dA = (a0 + b0 + c0 + d0) * sc;
  float dB = (a1 + b1 + c1 + d1) * sc;
  dA += __shfl_xor(dA, 1); dB += __shfl_xor(dB, 1);
  dA += __shfl_xor(dA, 2); dB += __shfl_xor(dB, 2);
  if (r == 0){
    int n = k >> 2;
    float mx = fmaxf(dA, dB);
    float e0 = __expf(dA - mx), e1 = __expf(dB - mx);
    float inv = 1.0f / (e0 + e1);
    *(float2*)(out + 2 * n) = (float2){e0 * inv, e1 * inv};            // softmax [N,2]
    *(float2*)(out + 2 * N_NODES + 2 * n) = (float2){dA, dB};          // logits  [N,2]
  }
}

// ---------------- launch: 9 dispatches (was 14) ----------------

extern "C" void kernel_launch(void* const* d_in, const int* in_sizes, int n_in,
                              void* d_out, int out_size, void* d_ws, size_t ws_size,
                              hipStream_t stream){
  const float* x  = (const float*)d_in[0];
  const int* ei   = (const int*)d_in[1];
  const int* et   = (const int*)d_in[2];
  const float* W1 = (const float*)d_in[3];
  const float* W2 = (const float*)d_in[4];
  const float* W3 = (const float*)d_in[5];
  float* out = (float*)d_out;
  const int* src = ei;
  const int* dst = ei + N_EDGES;

  // workspace layout: ~62 MB total
  char* p = (char*)d_ws;
  auto alloc = [&](size_t bytes) -> char* {
    char* q = p; p += (bytes + 63) & ~(size_t)63; return q;
  };
  int* counts = (int*)alloc((size_t)NKEY * 4);          // reused as cursor
  int* cursor = counts;
  char* zrow  = alloc(256);              // adjacent to counts: one memset covers both
  int* offs   = (int*)alloc((size_t)(NKEY + 1) * 4);
  int* bsums  = (int*)alloc(1024 * 4);
  int* ssrc   = (int*)alloc((size_t)N_EDGES * 4);
  unsigned short* Bt1 = (unsigned short*)alloc((size_t)DDIM * KDIM * 2);
  unsigned short* Bt2 = (unsigned short*)alloc((size_t)DDIM * KDIM * 2);
  unsigned short* h1 = (unsigned short*)alloc((size_t)N_NODES * DDIM * 2);
  unsigned short* h2 = (unsigned short*)alloc((size_t)N_NODES * DDIM * 2);
  unsigned* xb = (unsigned*)h2;   // x-as-bf16 lives in h2's slot (dead until layer-2 output)
  float* zt = (float*)h1;         // z table aliases h1 (dead after layer-2 reads it)

  // 1 memset: counts + zrow (adjacent)
  hipMemsetAsync(counts, 0, (size_t)NKEY * 4 + 256, stream);
  // hist + convert_x + transpose W1 + transpose W2, fused
  mega_prep<<<HB + CB + 2 * TB, 256, 0, stream>>>(dst, et, counts, x, xb, W1, Bt1, W2, Bt2);
  int nb = (NKEY + 1023) / 1024;  // 391
  scan_local<<<nb, 1024, 0, stream>>>(counts, offs, bsums, NKEY);
  scan_add2<<<nb, 1024, 0, stream>>>(offs, cursor, bsums, NKEY, nb, 0);
  scatter_kernel<<<N_EDGES / 256, 256, 0, stream>>>(src, dst, et, cursor, ssrc);

  int fgrid = (N_NODES + 63) / 64;  // 1563

  fused_layer<<<fgrid, 256, 0, stream>>>(xb, ssrc, offs, (const __bf16*)Bt1, zrow, h1);
  fused_layer<<<fgrid, 256, 0, stream>>>((const unsigned*)h1, ssrc, offs, (const __bf16*)Bt2, zrow, h2);
  compute_z<<<N_NODES / 4, 256, 0, stream>>>((const unsigned*)h2, W3, zt);
  fused_head2<<<(NKEY + 255) / 256, 256, 0, stream>>>(zt, ssrc, offs, out);
}

// Round 13
// 735.271 us; speedup vs baseline: 3.7730x; 1.0214x over previous
//
#include <hip/hip_runtime.h>
#include <math.h>

#define N_NODES 100000
#define N_EDGES 1600000
#define RREL 4
#define DDIM 128
#define KDIM 512      // RREL*DDIM
#define NKEY 400000   // N_NODES*RREL

// mega_prep block ranges
#define HB 6250       // hist blocks
#define CB 25000      // convert_x blocks
#define TB 256        // transpose blocks (each)

typedef __bf16 bf16x8 __attribute__((ext_vector_type(8)));
typedef float f32x4 __attribute__((ext_vector_type(4)));

__device__ __forceinline__ float bflo(unsigned u){ return __builtin_bit_cast(float, u << 16); }
__device__ __forceinline__ float bfhi(unsigned u){ return __builtin_bit_cast(float, u & 0xffff0000u); }
__device__ __forceinline__ unsigned f2bf(float f){
  unsigned u = __builtin_bit_cast(unsigned, f);
  return (u + 0x7fffu + ((u >> 16) & 1u)) >> 16;   // RNE, finite inputs
}
__device__ __forceinline__ int iclamp(int v, int lo, int hi){
  return v < lo ? lo : (v > hi ? hi : v);
}

#define GLL(gp, lp) __builtin_amdgcn_global_load_lds( \
    (const __attribute__((address_space(1))) void*)(gp), \
    (__attribute__((address_space(3))) void*)(lp), 16, 0, 0)

// ---------------- mega prep: hist + convert_x + transpose W1/W2 ----------------

__global__ void mega_prep(const int* __restrict__ dst, const int* __restrict__ et,
                          int* __restrict__ counts,
                          const float* __restrict__ x, unsigned* __restrict__ xb,
                          const float* __restrict__ W1, unsigned short* __restrict__ Bt1,
                          const float* __restrict__ W2, unsigned short* __restrict__ Bt2){
  int b = blockIdx.x, t = threadIdx.x;
  if (b < HB){
    int e = b * 256 + t;
    int key = iclamp(dst[e] * RREL + et[e], 0, NKEY - 1);
    atomicAdd(&counts[key], 1);
  } else if (b < HB + CB){
    int i = (b - HB) * 256 + t;                 // over N*64
    float2 v = *(const float2*)(x + (size_t)i * 2);
    xb[i] = f2bf(v.x) | (f2bf(v.y) << 16);
  } else if (b < HB + CB + TB){
    int idx = (b - HB - CB) * 256 + t;          // 65536
    int k = idx >> 7, n = idx & 127;
    Bt1[n * KDIM + k] = (unsigned short)f2bf(W1[idx]);
  } else {
    int idx = (b - HB - CB - TB) * 256 + t;
    int k = idx >> 7, n = idx & 127;
    Bt2[n * KDIM + k] = (unsigned short)f2bf(W2[idx]);
  }
}

// ---------------- scan: 2 dispatches ----------------

__global__ void scan_local(const int* __restrict__ in, int* __restrict__ out,
                           int* __restrict__ bsums, int K){
  __shared__ int s[1024];
  int t = threadIdx.x;
  int i = blockIdx.x * 1024 + t;
  int v = (i < K) ? in[i] : 0;
  s[t] = v; __syncthreads();
  for (int off = 1; off < 1024; off <<= 1){
    int x = (t >= off) ? s[t - off] : 0;
    __syncthreads();
    s[t] += x;
    __syncthreads();
  }
  if (i < K) out[i] = s[t] - v;           // exclusive within block
  if (t == 1023) bsums[blockIdx.x] = s[t];
}

__global__ void scan_add2(int* __restrict__ out, int* __restrict__ cursor,
                          const int* __restrict__ bsums, int K, int nb, int total_unused){
  __shared__ int base_s;
  int t = threadIdx.x, bid = blockIdx.x;
  if (t < 64){
    int s = 0;
    for (int j = t; j < bid; j += 64) s += bsums[j];
    #pragma unroll
    for (int m = 32; m >= 1; m >>= 1) s += __shfl_xor(s, m);
    if (t == 0) base_s = s;
  }
  __syncthreads();
  int base = base_s;
  int i = bid * 1024 + t;
  if (i < K){
    int v = out[i] + base;
    out[i] = v;
    cursor[i] = v;
  }
  if (bid == 0 && t < 64){
    int s = 0;
    for (int j = t; j < nb; j += 64) s += bsums[j];
    #pragma unroll
    for (int m = 32; m >= 1; m >>= 1) s += __shfl_xor(s, m);
    if (t == 0) out[K] = s;               // total
  }
}

__global__ void scatter_kernel(const int* __restrict__ src, const int* __restrict__ dst,
                               const int* __restrict__ et, int* __restrict__ cursor,
                               int* __restrict__ ssrc){
  int e = blockIdx.x * 256 + threadIdx.x;
  int key = iclamp(dst[e] * RREL + et[e], 0, NKEY - 1);
  int p = atomicAdd(&cursor[key], 1);
  p = iclamp(p, 0, N_EDGES - 1);
  ssrc[p] = iclamp(src[e], 0, N_NODES - 1);
}

// ---------------- fused layer: LDS-staged gather -> mean -> @W -> tanh ----------------
// r11 pipeline unchanged (at the per-CU MSHR x latency wall). r13 change: block = 128
// threads / 2 waves / 32 nodes / 16 KB LDS -> 3125 blocks, 10 resident blocks per CU
// (same 20-wave steady state, 2x finer scheduling granularity). Waves never interact;
// blocks are pure scheduling containers — this targets the CU-level makespan tail
// (measured 18 cy/line vs ~11 cy/line MSHR floor; occupancy 18% vs 62% theoretical).

__global__ __launch_bounds__(128) void fused_layer(const unsigned* __restrict__ hin,
                                                   const int* __restrict__ ssrc,
                                                   const int* __restrict__ offs,
                                                   const __bf16* __restrict__ Bt,
                                                   const char* __restrict__ zrow,
                                                   unsigned short* __restrict__ hout){
  __shared__ uint4 smem4[1024];          // 2 waves x 2 bufs x 16 rows x 256 B = 16 KB

  int tid = threadIdx.x;
  int w = tid >> 6, lane = tid & 63;
  int l15 = lane & 15, quad = lane >> 4;
  int n0w = blockIdx.x * 32 + w * 16;
  int n = n0w + l15;                     // this lane's node
  int valid = (n < N_NODES);
  const char* hinB = (const char*)hin;
  uint4* lw = &smem4[w << 9];            // this wave's 512-uint4 region

  f32x4 accC[8];
  #pragma unroll
  for (int tc = 0; tc < 8; tc++) accC[tc] = (f32x4){0.f, 0.f, 0.f, 0.f};

  int q0 = (l15 ^ (quad)) * 16;
  int q1 = (l15 ^ (4 + quad)) * 16;
  int q2 = (l15 ^ (8 + quad)) * 16;
  int q3 = (l15 ^ (12 + quad)) * 16;

  #pragma unroll
  for (int r = 0; r < RREL; r++){
    int ob = valid ? (n * 4 + r) : 0;
    int beg = iclamp(offs[ob], 0, N_EDGES);
    int end = iclamp(offs[ob + 1], beg, N_EDGES);
    if (!valid){ beg = 0; end = 0; }
    int deg = end - beg;

    int trip = deg;                      // wave-uniform step count = max degree
    #pragma unroll
    for (int k = 1; k < 64; k <<= 1){
      int o = __shfl_xor(trip, k);
      trip = trip > o ? trip : o;
    }

    float ac[32];
    #pragma unroll
    for (int j = 0; j < 32; j++) ac[j] = 0.f;

    if (trip > 0){
      int bg0 = __shfl(beg, quad),      eg0 = __shfl(end, quad);
      int bg1 = __shfl(beg, 4 + quad),  eg1 = __shfl(end, 4 + quad);
      int bg2 = __shfl(beg, 8 + quad),  eg2 = __shfl(end, 8 + quad);
      int bg3 = __shfl(beg, 12 + quad), eg3 = __shfl(end, 12 + quad);

      int svA0 = ssrc[iclamp(bg0, 0, N_EDGES - 1)];
      int svA1 = ssrc[iclamp(bg1, 0, N_EDGES - 1)];
      int svA2 = ssrc[iclamp(bg2, 0, N_EDGES - 1)];
      int svA3 = ssrc[iclamp(bg3, 0, N_EDGES - 1)];
      {
        const char* a0 = (0 < eg0 - bg0) ? hinB + (size_t)(unsigned)svA0 * 256 + q0 : zrow + q0;
        const char* a1 = (0 < eg1 - bg1) ? hinB + (size_t)(unsigned)svA1 * 256 + q1 : zrow + q1;
        const char* a2 = (0 < eg2 - bg2) ? hinB + (size_t)(unsigned)svA2 * 256 + q2 : zrow + q2;
        const char* a3 = (0 < eg3 - bg3) ? hinB + (size_t)(unsigned)svA3 * 256 + q3 : zrow + q3;
        GLL(a0, lw + 0);
        GLL(a1, lw + 64);
        GLL(a2, lw + 128);
        GLL(a3, lw + 192);
      }
      svA0 = ssrc[iclamp(bg0 + 1, 0, N_EDGES - 1)];
      svA1 = ssrc[iclamp(bg1 + 1, 0, N_EDGES - 1)];
      svA2 = ssrc[iclamp(bg2 + 1, 0, N_EDGES - 1)];
      svA3 = ssrc[iclamp(bg3 + 1, 0, N_EDGES - 1)];

      for (int i = 0; i < trip; i++){
        int b = i & 1;
        asm volatile("s_waitcnt vmcnt(0)" ::: "memory");
        __builtin_amdgcn_sched_barrier(0);
        if (i + 1 < trip){
          uint4* db = lw + ((b ^ 1) << 8);
          const char* a0 = (i + 1 < eg0 - bg0) ? hinB + (size_t)(unsigned)svA0 * 256 + q0 : zrow + q0;
          const char* a1 = (i + 1 < eg1 - bg1) ? hinB + (size_t)(unsigned)svA1 * 256 + q1 : zrow + q1;
          const char* a2 = (i + 1 < eg2 - bg2) ? hinB + (size_t)(unsigned)svA2 * 256 + q2 : zrow + q2;
          const char* a3 = (i + 1 < eg3 - bg3) ? hinB + (size_t)(unsigned)svA3 * 256 + q3 : zrow + q3;
          GLL(a0, db + 0);
          GLL(a1, db + 64);
          GLL(a2, db + 128);
          GLL(a3, db + 192);
          svA0 = ssrc[iclamp(bg0 + i + 2, 0, N_EDGES - 1)];
          svA1 = ssrc[iclamp(bg1 + i + 2, 0, N_EDGES - 1)];
          svA2 = ssrc[iclamp(bg2 + i + 2, 0, N_EDGES - 1)];
          svA3 = ssrc[iclamp(bg3 + i + 2, 0, N_EDGES - 1)];
        }

        const uint4* rb = lw + (b << 8) + (l15 << 4);
        uint4 u0 = rb[(0 * 4 + quad) ^ l15];
        uint4 u1 = rb[(1 * 4 + quad) ^ l15];
        uint4 u2 = rb[(2 * 4 + quad) ^ l15];
        uint4 u3 = rb[(3 * 4 + quad) ^ l15];
        ac[ 0] += bflo(u0.x); ac[ 1] += bfhi(u0.x); ac[ 2] += bflo(u0.y); ac[ 3] += bfhi(u0.y);
        ac[ 4] += bflo(u0.z); ac[ 5] += bfhi(u0.z); ac[ 6] += bflo(u0.w); ac[ 7] += bfhi(u0.w);
        ac[ 8] += bflo(u1.x); ac[ 9] += bfhi(u1.x); ac[10] += bflo(u1.y); ac[11] += bfhi(u1.y);
        ac[12] += bflo(u1.z); ac[13] += bfhi(u1.z); ac[14] += bflo(u1.w); ac[15] += bfhi(u1.w);
        ac[16] += bflo(u2.x); ac[17] += bfhi(u2.x); ac[18] += bflo(u2.y); ac[19] += bfhi(u2.y);
        ac[20] += bflo(u2.z); ac[21] += bfhi(u2.z); ac[22] += bflo(u2.w); ac[23] += bfhi(u2.w);
        ac[24] += bflo(u3.x); ac[25] += bfhi(u3.x); ac[26] += bflo(u3.y); ac[27] += bfhi(u3.y);
        ac[28] += bflo(u3.z); ac[29] += bfhi(u3.z); ac[30] += bflo(u3.w); ac[31] += bfhi(u3.w);
      }
    }

    float sc = (deg > 0) ? 1.0f / (float)deg : 0.0f;

    #pragma unroll
    for (int s = 0; s < 4; s++){
      uint4 pv;
      pv.x = f2bf(ac[s * 8 + 0] * sc) | (f2bf(ac[s * 8 + 1] * sc) << 16);
      pv.y = f2bf(ac[s * 8 + 2] * sc) | (f2bf(ac[s * 8 + 3] * sc) << 16);
      pv.z = f2bf(ac[s * 8 + 4] * sc) | (f2bf(ac[s * 8 + 5] * sc) << 16);
      pv.w = f2bf(ac[s * 8 + 6] * sc) | (f2bf(ac[s * 8 + 7] * sc) << 16);
      bf16x8 af = __builtin_bit_cast(bf16x8, pv);
      const __bf16* bbase = Bt + r * 128 + s * 32 + quad * 8;
      #pragma unroll
      for (int tc = 0; tc < 8; tc++){
        bf16x8 bfr = *(const bf16x8*)(bbase + (size_t)(tc * 16 + l15) * KDIM);
        accC[tc] = __builtin_amdgcn_mfma_f32_16x16x32_bf16(af, bfr, accC[tc], 0, 0, 0);
      }
    }
  }

  #pragma unroll
  for (int tc = 0; tc < 8; tc++){
    #pragma unroll
    for (int reg = 0; reg < 4; reg++){
      int n2 = n0w + quad * 4 + reg;
      if (n2 < N_NODES){
        float v = tanhf(accC[tc][reg]);
        hout[(size_t)n2 * 128 + tc * 16 + l15] = (unsigned short)f2bf(v);
      }
    }
  }
}

// ---------------- z precompute: z[n][r][2] = h2[n] . W3_r  (head linearity) ----------------

__global__ void compute_z(const unsigned* __restrict__ h2, const float* __restrict__ W3f,
                          float* __restrict__ zt){
  int n = blockIdx.x * 4 + (threadIdx.x >> 6);
  int lane = threadIdx.x & 63;
  unsigned u = h2[(size_t)n * 64 + lane];
  float a = bflo(u), b = bfhi(u);
  float p[8];
  #pragma unroll
  for (int r = 0; r < RREL; r++){
    float4 wv = *(const float4*)(W3f + r * 256 + lane * 4);
    p[r * 2]     = a * wv.x + b * wv.z;
    p[r * 2 + 1] = a * wv.y + b * wv.w;
  }
  #pragma unroll
  for (int m = 32; m >= 1; m >>= 1){
    #pragma unroll
    for (int j = 0; j < 8; j++) p[j] += __shfl_xor(p[j], m);
  }
  if (lane == 0){
    *(float4*)(zt + (size_t)n * 8)     = (float4){p[0], p[1], p[2], p[3]};
    *(float4*)(zt + (size_t)n * 8 + 4) = (float4){p[4], p[5], p[6], p[7]};
  }
}

// ---------------- head: thread per (node,rel) key; mean of z[src,rel] -> reduce -> softmax ----

__global__ void fused_head2(const float* __restrict__ zt,
                            const int* __restrict__ ssrc,
                            const int* __restrict__ offs,
                            float* __restrict__ out){
  int k = blockIdx.x * 256 + threadIdx.x;
  if (k >= NKEY) return;                  // whole waves exit; 4-groups stay intact
  int r = k & 3;
  int beg = iclamp(offs[k], 0, N_EDGES);
  int end = iclamp(offs[k + 1], beg, N_EDGES);
  float a0 = 0.f, a1 = 0.f, b0 = 0.f, b1 = 0.f, c0 = 0.f, c1 = 0.f, d0 = 0.f, d1 = 0.f;
  int i = beg;
  for (; i + 4 <= end; i += 4){
    int s0 = iclamp(ssrc[i],     0, N_NODES - 1);
    int s1 = iclamp(ssrc[i + 1], 0, N_NODES - 1);
    int s2 = iclamp(ssrc[i + 2], 0, N_NODES - 1);
    int s3 = iclamp(ssrc[i + 3], 0, N_NODES - 1);
    float2 v0 = *(const float2*)(zt + (size_t)s0 * 8 + r * 2);
    float2 v1 = *(const float2*)(zt + (size_t)s1 * 8 + r * 2);
    float2 v2 = *(const float2*)(zt + (size_t)s2 * 8 + r * 2);
    float2 v3 = *(const float2*)(zt + (size_t)s3 * 8 + r * 2);
    a0 += v0.x; a1 += v0.y;
    b0 += v1.x; b1 += v1.y;
    c0 += v2.x; c1 += v2.y;
    d0 += v3.x; d1 += v3.y;
  }
  for (; i < end; i++){
    int s = iclamp(ssrc[i], 0, N_NODES - 1);
    float2 v = *(const float2*)(zt + (size_t)s * 8 + r * 2);
    a0 += v.x; a1 += v.y;
  }
  int cnt = end - beg;
  float sc = (cnt > 0) ? 1.0f / (float)cnt : 0.0f;
  float dA = (a0 + b0 + c0 + d0) * sc;
  float dB = (a1 + b1 + c1 + d1) * sc;
  dA += __shfl_xor(dA, 1); dB += __shfl_xor(dB, 1);
  dA += __shfl_xor(dA, 2); dB += __shfl_xor(dB, 2);
  if (r == 0){
    int n = k >> 2;
    float mx = fmaxf(dA, dB);
    float e0 = __expf(dA - mx), e1 = __expf(dB - mx);
    float inv = 1.0f / (e0 + e1);
    *(float2*)(out + 2 * n) = (float2){e0 * inv, e1 * inv};            // softmax [N,2]
    *(float2*)(out + 2 * N_NODES + 2 * n) = (float2){dA, dB};          // logits  [N,2]
  }
}

// ---------------- launch: 9 dispatches ----------------

extern "C" void kernel_launch(void* const* d_in, const int* in_sizes, int n_in,
                              void* d_out, int out_size, void* d_ws, size_t ws_size,
                              hipStream_t stream){
  const float* x  = (const float*)d_in[0];
  const int* ei   = (const int*)d_in[1];
  const int* et   = (const int*)d_in[2];
  const float* W1 = (const float*)d_in[3];
  const float* W2 = (const float*)d_in[4];
  const float* W3 = (const float*)d_in[5];
  float* out = (float*)d_out;
  const int* src = ei;
  const int* dst = ei + N_EDGES;

  // workspace layout: ~62 MB total
  char* p = (char*)d_ws;
  auto alloc = [&](size_t bytes) -> char* {
    char* q = p; p += (bytes + 63) & ~(size_t)63; return q;
  };
  int* counts = (int*)alloc((size_t)NKEY * 4);          // reused as cursor
  int* cursor = counts;
  char* zrow  = alloc(256);              // adjacent to counts: one memset covers both
  int* offs   = (int*)alloc((size_t)(NKEY + 1) * 4);
  int* bsums  = (int*)alloc(1024 * 4);
  int* ssrc   = (int*)alloc((size_t)N_EDGES * 4);
  unsigned short* Bt1 = (unsigned short*)alloc((size_t)DDIM * KDIM * 2);
  unsigned short* Bt2 = (unsigned short*)alloc((size_t)DDIM * KDIM * 2);
  unsigned short* h1 = (unsigned short*)alloc((size_t)N_NODES * DDIM * 2);
  unsigned short* h2 = (unsigned short*)alloc((size_t)N_NODES * DDIM * 2);
  unsigned* xb = (unsigned*)h2;   // x-as-bf16 lives in h2's slot (dead until layer-2 output)
  float* zt = (float*)h1;         // z table aliases h1 (dead after layer-2 reads it)

  hipMemsetAsync(counts, 0, (size_t)NKEY * 4 + 256, stream);
  mega_prep<<<HB + CB + 2 * TB, 256, 0, stream>>>(dst, et, counts, x, xb, W1, Bt1, W2, Bt2);
  int nb = (NKEY + 1023) / 1024;  // 391
  scan_local<<<nb, 1024, 0, stream>>>(counts, offs, bsums, NKEY);
  scan_add2<<<nb, 1024, 0, stream>>>(offs, cursor, bsums, NKEY, nb, 0);
  scatter_kernel<<<N_EDGES / 256, 256, 0, stream>>>(src, dst, et, cursor, ssrc);

  int fgrid = (N_NODES + 31) / 32;  // 3125 blocks of 2 waves / 32 nodes

  fused_layer<<<fgrid, 128, 0, stream>>>(xb, ssrc, offs, (const __bf16*)Bt1, zrow, h1);
  fused_layer<<<fgrid, 128, 0, stream>>>((const unsigned*)h1, ssrc, offs, (const __bf16*)Bt2, zrow, h2);
  compute_z<<<N_NODES / 4, 256, 0, stream>>>((const unsigned*)h2, W3, zt);
  fused_head2<<<(NKEY + 255) / 256, 256, 0, stream>>>(zt, ssrc, offs, out);
}

// Round 14
// 706.367 us; speedup vs baseline: 3.9274x; 1.0409x over previous
//
#include <hip/hip_runtime.h>
#include <math.h>

#define N_NODES 100000
#define N_EDGES 1600000
#define RREL 4
#define DDIM 128
#define KDIM 512      // RREL*DDIM
#define NKEY 400000   // N_NODES*RREL

// mega_prep block ranges
#define HB 6250       // hist blocks
#define CB 25000      // convert_x blocks
#define TB 256        // transpose blocks (each)

typedef __bf16 bf16x8 __attribute__((ext_vector_type(8)));
typedef float f32x4 __attribute__((ext_vector_type(4)));

__device__ __forceinline__ float bflo(unsigned u){ return __builtin_bit_cast(float, u << 16); }
__device__ __forceinline__ float bfhi(unsigned u){ return __builtin_bit_cast(float, u & 0xffff0000u); }
__device__ __forceinline__ unsigned f2bf(float f){
  unsigned u = __builtin_bit_cast(unsigned, f);
  return (u + 0x7fffu + ((u >> 16) & 1u)) >> 16;   // RNE, finite inputs
}
__device__ __forceinline__ int iclamp(int v, int lo, int hi){
  return v < lo ? lo : (v > hi ? hi : v);
}

#define GLL(gp, lp) __builtin_amdgcn_global_load_lds( \
    (const __attribute__((address_space(1))) void*)(gp), \
    (__attribute__((address_space(3))) void*)(lp), 16, 0, 0)

// ---------------- mega prep: hist + convert_x + transpose W1/W2 ----------------

__global__ void mega_prep(const int* __restrict__ dst, const int* __restrict__ et,
                          int* __restrict__ counts,
                          const float* __restrict__ x, unsigned* __restrict__ xb,
                          const float* __restrict__ W1, unsigned short* __restrict__ Bt1,
                          const float* __restrict__ W2, unsigned short* __restrict__ Bt2){
  int b = blockIdx.x, t = threadIdx.x;
  if (b < HB){
    int e = b * 256 + t;
    int key = iclamp(dst[e] * RREL + et[e], 0, NKEY - 1);
    atomicAdd(&counts[key], 1);
  } else if (b < HB + CB){
    int i = (b - HB) * 256 + t;                 // over N*64
    float2 v = *(const float2*)(x + (size_t)i * 2);
    xb[i] = f2bf(v.x) | (f2bf(v.y) << 16);
  } else if (b < HB + CB + TB){
    int idx = (b - HB - CB) * 256 + t;          // 65536
    int k = idx >> 7, n = idx & 127;
    Bt1[n * KDIM + k] = (unsigned short)f2bf(W1[idx]);
  } else {
    int idx = (b - HB - CB - TB) * 256 + t;
    int k = idx >> 7, n = idx & 127;
    Bt2[n * KDIM + k] = (unsigned short)f2bf(W2[idx]);
  }
}

// ---------------- scan: 2 dispatches ----------------

__global__ void scan_local(const int* __restrict__ in, int* __restrict__ out,
                           int* __restrict__ bsums, int K){
  __shared__ int s[1024];
  int t = threadIdx.x;
  int i = blockIdx.x * 1024 + t;
  int v = (i < K) ? in[i] : 0;
  s[t] = v; __syncthreads();
  for (int off = 1; off < 1024; off <<= 1){
    int x = (t >= off) ? s[t - off] : 0;
    __syncthreads();
    s[t] += x;
    __syncthreads();
  }
  if (i < K) out[i] = s[t] - v;           // exclusive within block
  if (t == 1023) bsums[blockIdx.x] = s[t];
}

__global__ void scan_add2(int* __restrict__ out, int* __restrict__ cursor,
                          const int* __restrict__ bsums, int K, int nb, int total_unused){
  __shared__ int base_s;
  int t = threadIdx.x, bid = blockIdx.x;
  if (t < 64){
    int s = 0;
    for (int j = t; j < bid; j += 64) s += bsums[j];
    #pragma unroll
    for (int m = 32; m >= 1; m >>= 1) s += __shfl_xor(s, m);
    if (t == 0) base_s = s;
  }
  __syncthreads();
  int base = base_s;
  int i = bid * 1024 + t;
  if (i < K){
    int v = out[i] + base;
    out[i] = v;
    cursor[i] = v;
  }
  if (bid == 0 && t < 64){
    int s = 0;
    for (int j = t; j < nb; j += 64) s += bsums[j];
    #pragma unroll
    for (int m = 32; m >= 1; m >>= 1) s += __shfl_xor(s, m);
    if (t == 0) out[K] = s;               // total
  }
}

__global__ void scatter_kernel(const int* __restrict__ src, const int* __restrict__ dst,
                               const int* __restrict__ et, int* __restrict__ cursor,
                               int* __restrict__ ssrc){
  int e = blockIdx.x * 256 + threadIdx.x;
  int key = iclamp(dst[e] * RREL + et[e], 0, NKEY - 1);
  int p = atomicAdd(&cursor[key], 1);
  p = iclamp(p, 0, N_EDGES - 1);
  ssrc[p] = iclamp(src[e], 0, N_NODES - 1);
}

// ---------------- fused layer: LDS-staged gather -> mean -> @W -> [tanh->store | z-epilogue] --
// Gather/MFMA pipeline unchanged (at the per-CU line-service wall; 5 structures converge
// to ~200us/layer). FUSE_Z=1 (layer 2): instead of storing h2 (25.6 MB) for a separate
// compute_z pass (re-reading 25.6 MB), compute z[n][r][2] = tanh(h2[n]) . W3_r directly
// from the f32 accumulators: per reg, each 16-lane (l15) group holds all 128 dims ->
// partial dot over this lane's 8 dims, shfl_xor reduce over l15, lane 0 writes 8 f32.
// Kills one dispatch + 51 MB of traffic; z from f32 tanh (closer to ref than bf16 h2).

template<int FUSE_Z>
__global__ __launch_bounds__(128) void fused_layer(const unsigned* __restrict__ hin,
                                                   const int* __restrict__ ssrc,
                                                   const int* __restrict__ offs,
                                                   const __bf16* __restrict__ Bt,
                                                   const char* __restrict__ zrow,
                                                   unsigned short* __restrict__ hout,
                                                   const float* __restrict__ W3f,
                                                   float* __restrict__ zt){
  __shared__ uint4 smem4[1024];          // 2 waves x 2 bufs x 16 rows x 256 B = 16 KB

  int tid = threadIdx.x;
  int w = tid >> 6, lane = tid & 63;
  int l15 = lane & 15, quad = lane >> 4;
  int n0w = blockIdx.x * 32 + w * 16;
  int n = n0w + l15;                     // this lane's node
  int valid = (n < N_NODES);
  const char* hinB = (const char*)hin;
  uint4* lw = &smem4[w << 9];            // this wave's 512-uint4 region

  f32x4 accC[8];
  #pragma unroll
  for (int tc = 0; tc < 8; tc++) accC[tc] = (f32x4){0.f, 0.f, 0.f, 0.f};

  int q0 = (l15 ^ (quad)) * 16;
  int q1 = (l15 ^ (4 + quad)) * 16;
  int q2 = (l15 ^ (8 + quad)) * 16;
  int q3 = (l15 ^ (12 + quad)) * 16;

  #pragma unroll
  for (int r = 0; r < RREL; r++){
    int ob = valid ? (n * 4 + r) : 0;
    int beg = iclamp(offs[ob], 0, N_EDGES);
    int end = iclamp(offs[ob + 1], beg, N_EDGES);
    if (!valid){ beg = 0; end = 0; }
    int deg = end - beg;

    int trip = deg;                      // wave-uniform step count = max degree
    #pragma unroll
    for (int k = 1; k < 64; k <<= 1){
      int o = __shfl_xor(trip, k);
      trip = trip > o ? trip : o;
    }

    float ac[32];
    #pragma unroll
    for (int j = 0; j < 32; j++) ac[j] = 0.f;

    if (trip > 0){
      int bg0 = __shfl(beg, quad),      eg0 = __shfl(end, quad);
      int bg1 = __shfl(beg, 4 + quad),  eg1 = __shfl(end, 4 + quad);
      int bg2 = __shfl(beg, 8 + quad),  eg2 = __shfl(end, 8 + quad);
      int bg3 = __shfl(beg, 12 + quad), eg3 = __shfl(end, 12 + quad);

      int svA0 = ssrc[iclamp(bg0, 0, N_EDGES - 1)];
      int svA1 = ssrc[iclamp(bg1, 0, N_EDGES - 1)];
      int svA2 = ssrc[iclamp(bg2, 0, N_EDGES - 1)];
      int svA3 = ssrc[iclamp(bg3, 0, N_EDGES - 1)];
      {
        const char* a0 = (0 < eg0 - bg0) ? hinB + (size_t)(unsigned)svA0 * 256 + q0 : zrow + q0;
        const char* a1 = (0 < eg1 - bg1) ? hinB + (size_t)(unsigned)svA1 * 256 + q1 : zrow + q1;
        const char* a2 = (0 < eg2 - bg2) ? hinB + (size_t)(unsigned)svA2 * 256 + q2 : zrow + q2;
        const char* a3 = (0 < eg3 - bg3) ? hinB + (size_t)(unsigned)svA3 * 256 + q3 : zrow + q3;
        GLL(a0, lw + 0);
        GLL(a1, lw + 64);
        GLL(a2, lw + 128);
        GLL(a3, lw + 192);
      }
      svA0 = ssrc[iclamp(bg0 + 1, 0, N_EDGES - 1)];
      svA1 = ssrc[iclamp(bg1 + 1, 0, N_EDGES - 1)];
      svA2 = ssrc[iclamp(bg2 + 1, 0, N_EDGES - 1)];
      svA3 = ssrc[iclamp(bg3 + 1, 0, N_EDGES - 1)];

      for (int i = 0; i < trip; i++){
        int b = i & 1;
        asm volatile("s_waitcnt vmcnt(0)" ::: "memory");
        __builtin_amdgcn_sched_barrier(0);
        if (i + 1 < trip){
          uint4* db = lw + ((b ^ 1) << 8);
          const char* a0 = (i + 1 < eg0 - bg0) ? hinB + (size_t)(unsigned)svA0 * 256 + q0 : zrow + q0;
          const char* a1 = (i + 1 < eg1 - bg1) ? hinB + (size_t)(unsigned)svA1 * 256 + q1 : zrow + q1;
          const char* a2 = (i + 1 < eg2 - bg2) ? hinB + (size_t)(unsigned)svA2 * 256 + q2 : zrow + q2;
          const char* a3 = (i + 1 < eg3 - bg3) ? hinB + (size_t)(unsigned)svA3 * 256 + q3 : zrow + q3;
          GLL(a0, db + 0);
          GLL(a1, db + 64);
          GLL(a2, db + 128);
          GLL(a3, db + 192);
          svA0 = ssrc[iclamp(bg0 + i + 2, 0, N_EDGES - 1)];
          svA1 = ssrc[iclamp(bg1 + i + 2, 0, N_EDGES - 1)];
          svA2 = ssrc[iclamp(bg2 + i + 2, 0, N_EDGES - 1)];
          svA3 = ssrc[iclamp(bg3 + i + 2, 0, N_EDGES - 1)];
        }

        const uint4* rb = lw + (b << 8) + (l15 << 4);
        uint4 u0 = rb[(0 * 4 + quad) ^ l15];
        uint4 u1 = rb[(1 * 4 + quad) ^ l15];
        uint4 u2 = rb[(2 * 4 + quad) ^ l15];
        uint4 u3 = rb[(3 * 4 + quad) ^ l15];
        ac[ 0] += bflo(u0.x); ac[ 1] += bfhi(u0.x); ac[ 2] += bflo(u0.y); ac[ 3] += bfhi(u0.y);
        ac[ 4] += bflo(u0.z); ac[ 5] += bfhi(u0.z); ac[ 6] += bflo(u0.w); ac[ 7] += bfhi(u0.w);
        ac[ 8] += bflo(u1.x); ac[ 9] += bfhi(u1.x); ac[10] += bflo(u1.y); ac[11] += bfhi(u1.y);
        ac[12] += bflo(u1.z); ac[13] += bfhi(u1.z); ac[14] += bflo(u1.w); ac[15] += bfhi(u1.w);
        ac[16] += bflo(u2.x); ac[17] += bfhi(u2.x); ac[18] += bflo(u2.y); ac[19] += bfhi(u2.y);
        ac[20] += bflo(u2.z); ac[21] += bfhi(u2.z); ac[22] += bflo(u2.w); ac[23] += bfhi(u2.w);
        ac[24] += bflo(u3.x); ac[25] += bfhi(u3.x); ac[26] += bflo(u3.y); ac[27] += bfhi(u3.y);
        ac[28] += bflo(u3.z); ac[29] += bfhi(u3.z); ac[30] += bflo(u3.w); ac[31] += bfhi(u3.w);
      }
    }

    float sc = (deg > 0) ? 1.0f / (float)deg : 0.0f;

    #pragma unroll
    for (int s = 0; s < 4; s++){
      uint4 pv;
      pv.x = f2bf(ac[s * 8 + 0] * sc) | (f2bf(ac[s * 8 + 1] * sc) << 16);
      pv.y = f2bf(ac[s * 8 + 2] * sc) | (f2bf(ac[s * 8 + 3] * sc) << 16);
      pv.z = f2bf(ac[s * 8 + 4] * sc) | (f2bf(ac[s * 8 + 5] * sc) << 16);
      pv.w = f2bf(ac[s * 8 + 6] * sc) | (f2bf(ac[s * 8 + 7] * sc) << 16);
      bf16x8 af = __builtin_bit_cast(bf16x8, pv);
      const __bf16* bbase = Bt + r * 128 + s * 32 + quad * 8;
      #pragma unroll
      for (int tc = 0; tc < 8; tc++){
        bf16x8 bfr = *(const bf16x8*)(bbase + (size_t)(tc * 16 + l15) * KDIM);
        accC[tc] = __builtin_amdgcn_mfma_f32_16x16x32_bf16(af, bfr, accC[tc], 0, 0, 0);
      }
    }
  }

  if (FUSE_Z == 0){
    // epilogue: tanh, store bf16. C layout: col=l15, row=quad*4+reg
    #pragma unroll
    for (int tc = 0; tc < 8; tc++){
      #pragma unroll
      for (int reg = 0; reg < 4; reg++){
        int n2 = n0w + quad * 4 + reg;
        if (n2 < N_NODES){
          float v = tanhf(accC[tc][reg]);
          hout[(size_t)n2 * 128 + tc * 16 + l15] = (unsigned short)f2bf(v);
        }
      }
    }
  } else {
    // z-epilogue: z[n][r][2] = sum_d tanh(h2[n][d]) * W3[r][d][c].
    // 16-lane group (fixed quad) holds dims tc*16+l15 of nodes n0w+quad*4+reg.
    #pragma unroll
    for (int reg = 0; reg < 4; reg++){
      float zv[8];
      #pragma unroll
      for (int j = 0; j < 8; j++) zv[j] = 0.f;
      #pragma unroll
      for (int tc = 0; tc < 8; tc++){
        float t = tanhf(accC[tc][reg]);
        int dim = tc * 16 + l15;
        #pragma unroll
        for (int r4 = 0; r4 < 4; r4++){
          float2 wv = *(const float2*)(W3f + r4 * 256 + dim * 2);
          zv[r4 * 2]     += t * wv.x;
          zv[r4 * 2 + 1] += t * wv.y;
        }
      }
      #pragma unroll
      for (int m = 1; m <= 8; m <<= 1){
        #pragma unroll
        for (int j = 0; j < 8; j++) zv[j] += __shfl_xor(zv[j], m);
      }
      int n2 = n0w + quad * 4 + reg;
      if (l15 == 0 && n2 < N_NODES){
        *(float4*)(zt + (size_t)n2 * 8)     = (float4){zv[0], zv[1], zv[2], zv[3]};
        *(float4*)(zt + (size_t)n2 * 8 + 4) = (float4){zv[4], zv[5], zv[6], zv[7]};
      }
    }
  }
}

// ---------------- head: thread per (node,rel) key; mean of z[src,rel] -> reduce -> softmax ----

__global__ void fused_head2(const float* __restrict__ zt,
                            const int* __restrict__ ssrc,
                            const int* __restrict__ offs,
                            float* __restrict__ out){
  int k = blockIdx.x * 256 + threadIdx.x;
  if (k >= NKEY) return;                  // whole waves exit; 4-groups stay intact
  int r = k & 3;
  int beg = iclamp(offs[k], 0, N_EDGES);
  int end = iclamp(offs[k + 1], beg, N_EDGES);
  float a0 = 0.f, a1 = 0.f, b0 = 0.f, b1 = 0.f, c0 = 0.f, c1 = 0.f, d0 = 0.f, d1 = 0.f;
  int i = beg;
  for (; i + 4 <= end; i += 4){
    int s0 = iclamp(ssrc[i],     0, N_NODES - 1);
    int s1 = iclamp(ssrc[i + 1], 0, N_NODES - 1);
    int s2 = iclamp(ssrc[i + 2], 0, N_NODES - 1);
    int s3 = iclamp(ssrc[i + 3], 0, N_NODES - 1);
    float2 v0 = *(const float2*)(zt + (size_t)s0 * 8 + r * 2);
    float2 v1 = *(const float2*)(zt + (size_t)s1 * 8 + r * 2);
    float2 v2 = *(const float2*)(zt + (size_t)s2 * 8 + r * 2);
    float2 v3 = *(const float2*)(zt + (size_t)s3 * 8 + r * 2);
    a0 += v0.x; a1 += v0.y;
    b0 += v1.x; b1 += v1.y;
    c0 += v2.x; c1 += v2.y;
    d0 += v3.x; d1 += v3.y;
  }
  for (; i < end; i++){
    int s = iclamp(ssrc[i], 0, N_NODES - 1);
    float2 v = *(const float2*)(zt + (size_t)s * 8 + r * 2);
    a0 += v.x; a1 += v.y;
  }
  int cnt = end - beg;
  float sc = (cnt > 0) ? 1.0f / (float)cnt : 0.0f;
  float dA = (a0 + b0 + c0 + d0) * sc;
  float dB = (a1 + b1 + c1 + d1) * sc;
  dA += __shfl_xor(dA, 1); dB += __shfl_xor(dB, 1);
  dA += __shfl_xor(dA, 2); dB += __shfl_xor(dB, 2);
  if (r == 0){
    int n = k >> 2;
    float mx = fmaxf(dA, dB);
    float e0 = __expf(dA - mx), e1 = __expf(dB - mx);
    float inv = 1.0f / (e0 + e1);
    *(float2*)(out + 2 * n) = (float2){e0 * inv, e1 * inv};            // softmax [N,2]
    *(float2*)(out + 2 * N_NODES + 2 * n) = (float2){dA, dB};          // logits  [N,2]
  }
}

// ---------------- launch: 8 dispatches ----------------

extern "C" void kernel_launch(void* const* d_in, const int* in_sizes, int n_in,
                              void* d_out, int out_size, void* d_ws, size_t ws_size,
                              hipStream_t stream){
  const float* x  = (const float*)d_in[0];
  const int* ei   = (const int*)d_in[1];
  const int* et   = (const int*)d_in[2];
  const float* W1 = (const float*)d_in[3];
  const float* W2 = (const float*)d_in[4];
  const float* W3 = (const float*)d_in[5];
  float* out = (float*)d_out;
  const int* src = ei;
  const int* dst = ei + N_EDGES;

  // workspace layout: ~62 MB total
  char* p = (char*)d_ws;
  auto alloc = [&](size_t bytes) -> char* {
    char* q = p; p += (bytes + 63) & ~(size_t)63; return q;
  };
  int* counts = (int*)alloc((size_t)NKEY * 4);          // reused as cursor
  int* cursor = counts;
  char* zrow  = alloc(256);              // adjacent to counts: one memset covers both
  int* offs   = (int*)alloc((size_t)(NKEY + 1) * 4);
  int* bsums  = (int*)alloc(1024 * 4);
  int* ssrc   = (int*)alloc((size_t)N_EDGES * 4);
  unsigned short* Bt1 = (unsigned short*)alloc((size_t)DDIM * KDIM * 2);
  unsigned short* Bt2 = (unsigned short*)alloc((size_t)DDIM * KDIM * 2);
  unsigned short* h1 = (unsigned short*)alloc((size_t)N_NODES * DDIM * 2);
  char* slot2 = alloc((size_t)N_NODES * DDIM * 2);      // time-shared: xb then zt
  unsigned* xb = (unsigned*)slot2;  // x-as-bf16 (dead after layer 1)
  float* zt = (float*)slot2;        // z table, written by layer 2 (xb dead), read by head
                                    // NOTE: must NOT alias h1 — layer 2 reads h1 while writing zt

  hipMemsetAsync(counts, 0, (size_t)NKEY * 4 + 256, stream);
  mega_prep<<<HB + CB + 2 * TB, 256, 0, stream>>>(dst, et, counts, x, xb, W1, Bt1, W2, Bt2);
  int nb = (NKEY + 1023) / 1024;  // 391
  scan_local<<<nb, 1024, 0, stream>>>(counts, offs, bsums, NKEY);
  scan_add2<<<nb, 1024, 0, stream>>>(offs, cursor, bsums, NKEY, nb, 0);
  scatter_kernel<<<N_EDGES / 256, 256, 0, stream>>>(src, dst, et, cursor, ssrc);

  int fgrid = (N_NODES + 31) / 32;  // 3125 blocks of 2 waves / 32 nodes

  // layer 1: xb -> h1 (bf16 store epilogue)
  fused_layer<0><<<fgrid, 128, 0, stream>>>(xb, ssrc, offs, (const __bf16*)Bt1, zrow, h1,
                                            W3, nullptr);
  // layer 2: h1 -> z directly (no h2 materialization; z = tanh(h2) @ W3 per relation)
  fused_layer<1><<<fgrid, 128, 0, stream>>>((const unsigned*)h1, ssrc, offs,
                                            (const __bf16*)Bt2, zrow, nullptr, W3, zt);
  // head: 8 B/edge gather from 3.2 MB z table + softmax
  fused_head2<<<(NKEY + 255) / 256, 256, 0, stream>>>(zt, ssrc, offs, out);
}